// Round 13
// baseline (377.147 us; speedup 1.0000x reference)
//
#include <hip/hip_runtime.h>

typedef unsigned short ushort_t;
typedef short s16x8 __attribute__((ext_vector_type(8)));
typedef float f32x4 __attribute__((ext_vector_type(4)));

#define LN_EPS 1e-5f

// ---- bf16 <-> f32 helpers ----
__device__ __forceinline__ float b2f(ushort_t u) {
    return __uint_as_float(((unsigned)u) << 16);
}
__device__ __forceinline__ ushort_t f2b(float f) {
    unsigned b = __float_as_uint(f);
    b += 0x7FFFu + ((b >> 16) & 1u);  // round-to-nearest-even
    return (ushort_t)(b >> 16);
}
__device__ __forceinline__ unsigned f2b2(float lo, float hi) {  // pack two bf16
    return (unsigned)f2b(lo) | ((unsigned)f2b(hi) << 16);
}
// dtype-flexible load: isF ? fp32 : bf16
__device__ __forceinline__ float ldf(const void* p, size_t i, int isF) {
    return isF ? ((const float*)p)[i] : b2f(((const ushort_t*)p)[i]);
}

// harness-compat symbol (unused)
__global__ void GraphSAGE_36026185678961_kernel() {}

// ---------------- dtype detect (block 0) + zero-init deg, Z ----------------
__global__ void k_detect_zero(const void* w0, const void* ei, int* __restrict__ flags,
                              int* __restrict__ deg, float* __restrict__ Z, int N) {
    int i = blockIdx.x * blockDim.x + threadIdx.x;
    if (i < N) deg[i] = 0;
    if (i < 64 * 128) Z[i] = 0.f;
    if (blockIdx.x == 0 && threadIdx.x < 64) {
        int t = threadIdx.x;
        const ushort_t* u = (const ushort_t*)w0;
        int pass = 0;
        #pragma unroll
        for (int k = 0; k < 4; ++k) {
            ushort_t v = u[t * 4 + k];
            int ex = (v >> 7) & 0xFF;
            if (ex == 0 || (ex >= 0x60 && ex <= 0x7E)) pass++;
        }
        const unsigned* w = (const unsigned*)ei;
        int nz = (w[2 * t + 1] != 0u) ? 1 : 0;
        #pragma unroll
        for (int off = 32; off; off >>= 1) {
            pass += __shfl_down(pass, off, 64);
            nz += __shfl_down(nz, off, 64);
        }
        if (t == 0) {
            flags[0] = (pass < 205) ? 1 : 0;
            flags[1] = (nz == 0) ? 1 : 0;
        }
    }
}

// ---------------- fused prep: xconv | degree histogram | weight repack ----------------
// blocks [0,xb): x->bf16; [xb,xb+eb): hist; [xb+eb, ...): wprep.
// Wb0/Wb1: [128][256] (k<128 from Wl, else Wr). Wb2: [128][128] rows = stacked [Wl2;Wr2].
__global__ void k_prep(const void* X, ushort_t* __restrict__ XB, int total4, int xb,
                       const void* ei, int E, int N, int* __restrict__ deg, int eb,
                       const void* Wl0, const void* Wr0, const void* Wl1, const void* Wr1,
                       const void* Wl2, const void* Wr2,
                       ushort_t* __restrict__ Wb0, ushort_t* __restrict__ Wb1,
                       ushort_t* __restrict__ Wb2,
                       const int* __restrict__ flags) {
    int b = blockIdx.x;
    if (b < xb) {
        int idx = b * 256 + threadIdx.x;
        if (idx >= total4) return;
        if (flags[0]) {
            float4 v = ((const float4*)X)[idx];
            ushort4 o;
            o.x = f2b(v.x); o.y = f2b(v.y); o.z = f2b(v.z); o.w = f2b(v.w);
            ((ushort4*)XB)[idx] = o;
        } else {
            ((ushort4*)XB)[idx] = ((const ushort4*)X)[idx];
        }
    } else if (b < xb + eb) {
        int e = (b - xb) * 256 + threadIdx.x;
        if (e >= E) return;
        int d = flags[1] ? (int)((const long long*)ei)[E + e] : ((const int*)ei)[E + e];
        if ((unsigned)d < (unsigned)N) atomicAdd(&deg[d], 1);
    } else {
        int t = (b - xb - eb) * 256 + threadIdx.x;
        int isF = flags[0];
        if (t < 2 * 32768) {  // layers 0,1: [f][256]
            const void* Wl = (t < 32768) ? Wl0 : Wl1;
            const void* Wr = (t < 32768) ? Wr0 : Wr1;
            ushort_t* Wb = (t < 32768) ? Wb0 : Wb1;
            int base = t & 32767;
            int f = base >> 8, k = base & 255;
            if (isF) {
                float v = (k < 128) ? ((const float*)Wl)[f * 128 + k]
                                    : ((const float*)Wr)[f * 128 + (k - 128)];
                Wb[base] = f2b(v);
            } else {
                Wb[base] = ((const ushort_t*)((k < 128) ? Wl : Wr))[f * 128 + (k & 127)];
            }
        } else if (t < 2 * 32768 + 16384) {  // layer 2: [128][128], rows 0..63 Wl2, 64..127 Wr2
            int base = t - 2 * 32768;
            int f = base >> 7, k = base & 127;
            const void* W = (f < 64) ? Wl2 : Wr2;
            int fr = f & 63;
            Wb2[base] = isF ? f2b(((const float*)W)[fr * 128 + k])
                            : ((const ushort_t*)W)[fr * 128 + k];
        }
    }
}

// hierarchical scan, phase 1
__global__ void k_scan1(const int* __restrict__ deg, int N,
                        int* __restrict__ rowptr, int* __restrict__ bsum) {
    __shared__ int wsum[4];
    __shared__ int wpre[4];
    int tid = threadIdx.x;
    int lane = tid & 63;
    int w = tid >> 6;
    int i = blockIdx.x * 256 + tid;
    int v = (i < N) ? deg[i] : 0;
    int x = v;
    #pragma unroll
    for (int off = 1; off < 64; off <<= 1) {
        int t = __shfl_up(x, off, 64);
        if (lane >= off) x += t;
    }
    if (lane == 63) wsum[w] = x;
    __syncthreads();
    if (tid == 0) {
        int a = wsum[0]; wpre[0] = a;
        a += wsum[1]; wpre[1] = a;
        a += wsum[2]; wpre[2] = a;
        a += wsum[3]; wpre[3] = a;
    }
    __syncthreads();
    int woff = (w == 0) ? 0 : wpre[w - 1];
    if (i < N) rowptr[i] = woff + x - v;
    if (tid == 0) bsum[blockIdx.x] = wpre[3];
}

// phase 2: scan of block sums + graph bounds (fused)
__global__ void k_scan2(const int* __restrict__ bsum, int nb,
                        int* __restrict__ boff, int* __restrict__ rowptrN,
                        const void* batch, int N, int G, const int* __restrict__ flags,
                        int* __restrict__ bounds) {
    __shared__ int wsum[4];
    __shared__ int wpre[4];
    int tid = threadIdx.x;
    int lane = tid & 63;
    int w = tid >> 6;
    int run = 0;
    for (int base = 0; base < nb; base += 256) {
        int i = base + tid;
        int v = (i < nb) ? bsum[i] : 0;
        int x = v;
        #pragma unroll
        for (int off = 1; off < 64; off <<= 1) {
            int t = __shfl_up(x, off, 64);
            if (lane >= off) x += t;
        }
        if (lane == 63) wsum[w] = x;
        __syncthreads();
        if (tid == 0) {
            int a = wsum[0]; wpre[0] = a;
            a += wsum[1]; wpre[1] = a;
            a += wsum[2]; wpre[2] = a;
            a += wsum[3]; wpre[3] = a;
        }
        __syncthreads();
        int woff = (w == 0) ? 0 : wpre[w - 1];
        if (i < nb) boff[i] = run + woff + x - v;
        int tot = wpre[3];
        __syncthreads();
        run += tot;
    }
    if (tid == 0) *rowptrN = run;
    if (tid <= G) {
        int isL = flags[1];
        int lo = 0, hi = N;
        while (lo < hi) {
            int mid = (lo + hi) >> 1;
            int bv = isL ? (int)((const long long*)batch)[mid] : ((const int*)batch)[mid];
            if (bv < tid) lo = mid + 1; else hi = mid;
        }
        bounds[tid] = lo;
    }
}

// phase 3
__global__ void k_scan3(int* __restrict__ rowptr, const int* __restrict__ boff,
                        int* __restrict__ cursor, int N) {
    int i = blockIdx.x * 256 + threadIdx.x;
    if (i < N) {
        int r = rowptr[i] + boff[i >> 8];
        rowptr[i] = r;
        cursor[i] = r;
    }
}

// CSR fill (reads edge_index directly)
__global__ void k_fill(const void* ei, int E, int N, const int* __restrict__ flags,
                       int* __restrict__ cursor, int* __restrict__ col) {
    int e = blockIdx.x * blockDim.x + threadIdx.x;
    if (e >= E) return;
    int s, d;
    if (flags[1]) {
        const long long* p = (const long long*)ei;
        s = (int)p[e];
        d = (int)p[E + e];
    } else {
        const int* p = (const int*)ei;
        s = p[e];
        d = p[E + e];
    }
    if ((unsigned)d < (unsigned)N) {
        int p = atomicAdd(&cursor[d], 1);
        if ((unsigned)p < (unsigned)E) col[p] = ((unsigned)s < (unsigned)N) ? s : 0;
    }
}

// ---------------- mean aggregation: AGG[i] = mean_{j in N(i)} X[j]  (bf16, 128-wide) ----------------
__global__ __launch_bounds__(256) void k_agg(
    const ushort_t* __restrict__ X, const int* __restrict__ rowptr,
    const int* __restrict__ col, ushort_t* __restrict__ AGG, int N) {
    int i = blockIdx.x * 4 + (threadIdx.x >> 6);
    if (i >= N) return;
    int l = threadIdx.x & 63;
    int qn = l >> 4;   // neighbor slot 0..3
    int fo = l & 15;   // feature octet
    const uint4* X8 = (const uint4*)X;  // row = 16 uint4 groups
    int s = rowptr[i], e = rowptr[i + 1];
    float al[4] = {0.f, 0.f, 0.f, 0.f};
    float ah[4] = {0.f, 0.f, 0.f, 0.f};
    int p = s + qn;
    for (; p + 4 < e; p += 8) {
        int j0 = col[p], j1 = col[p + 4];
        uint4 u0 = X8[(size_t)j0 * 16 + fo];
        uint4 u1 = X8[(size_t)j1 * 16 + fo];
        unsigned w0[4] = {u0.x, u0.y, u0.z, u0.w};
        unsigned w1[4] = {u1.x, u1.y, u1.z, u1.w};
        #pragma unroll
        for (int k = 0; k < 4; ++k) {
            al[k] += __uint_as_float(w0[k] << 16) + __uint_as_float(w1[k] << 16);
            ah[k] += __uint_as_float(w0[k] & 0xFFFF0000u) + __uint_as_float(w1[k] & 0xFFFF0000u);
        }
    }
    for (; p < e; p += 4) {
        int j = col[p];
        uint4 u = X8[(size_t)j * 16 + fo];
        unsigned w0[4] = {u.x, u.y, u.z, u.w};
        #pragma unroll
        for (int k = 0; k < 4; ++k) {
            al[k] += __uint_as_float(w0[k] << 16);
            ah[k] += __uint_as_float(w0[k] & 0xFFFF0000u);
        }
    }
    #pragma unroll
    for (int k = 0; k < 4; ++k) {
        al[k] += __shfl_xor(al[k], 16, 64);
        al[k] += __shfl_xor(al[k], 32, 64);
        ah[k] += __shfl_xor(ah[k], 16, 64);
        ah[k] += __shfl_xor(ah[k], 32, 64);
    }
    if (qn == 0) {
        int d = e - s;
        float inv = 1.f / (float)(d > 0 ? d : 1);
        uint4 o;
        o.x = f2b2(al[0] * inv, ah[0] * inv);
        o.y = f2b2(al[1] * inv, ah[1] * inv);
        o.z = f2b2(al[2] * inv, ah[2] * inv);
        o.w = f2b2(al[3] * inv, ah[3] * inv);
        ((uint4*)AGG)[(size_t)i * 16 + fo] = o;
    }
}

// ---------------- fused MFMA GEMM + bias + LayerNorm + ReLU (layers 0,1) ----------------
template <int FO>
__global__ __launch_bounds__(256, 2) void k_gemm_ln(
    const ushort_t* __restrict__ AGG, const ushort_t* __restrict__ X,
    const ushort_t* __restrict__ Wb,  // [FO][256] bf16
    const void* bl, const void* gam, const void* bet,
    const int* __restrict__ flags,
    ushort_t* __restrict__ H, int M) {
    constexpr int NT = FO / 16;
    constexpr int R = 2;
    int lane = threadIdx.x & 63;
    int wid = threadIdx.x >> 6;
    int wrow0 = (blockIdx.x * 4 + wid) * (R * 16);
    if (wrow0 >= M) return;
    int isF = flags[0];
    int m = lane & 15;
    int q = lane >> 4;

    int arow[R];
    #pragma unroll
    for (int r = 0; r < R; ++r) {
        int ar = wrow0 + r * 16 + m;
        arow[r] = (ar < M) ? ar : (M - 1);
    }

    f32x4 acc[R][NT];
    #pragma unroll
    for (int r = 0; r < R; ++r)
        #pragma unroll
        for (int nt = 0; nt < NT; ++nt) acc[r][nt] = (f32x4){0.f, 0.f, 0.f, 0.f};

    #pragma unroll
    for (int kk = 0; kk < 8; ++kk) {
        const ushort_t* base = (kk < 4) ? AGG : X;
        int ko = (kk & 3) * 32 + q * 8;
        s16x8 a[R];
        #pragma unroll
        for (int r = 0; r < R; ++r)
            a[r] = *(const s16x8*)(base + (size_t)arow[r] * 128 + ko);
        #pragma unroll
        for (int nt = 0; nt < NT; ++nt) {
            s16x8 b = *(const s16x8*)(Wb + (size_t)(nt * 16 + m) * 256 + kk * 32 + q * 8);
            #pragma unroll
            for (int r = 0; r < R; ++r)
                acc[r][nt] = __builtin_amdgcn_mfma_f32_16x16x32_bf16(a[r], b, acc[r][nt], 0, 0, 0);
        }
    }

    #pragma unroll
    for (int r = 0; r < R; ++r) {
        #pragma unroll
        for (int nt = 0; nt < NT; ++nt) {
            float bv = ldf(bl, nt * 16 + m, isF);
            #pragma unroll
            for (int rr = 0; rr < 4; ++rr) acc[r][nt][rr] += bv;
        }
        float mu[4], rs[4];
        #pragma unroll
        for (int rr = 0; rr < 4; ++rr) {
            float s1 = 0.f, s2 = 0.f;
            #pragma unroll
            for (int nt = 0; nt < NT; ++nt) {
                float v = acc[r][nt][rr];
                s1 += v;
                s2 += v * v;
            }
            #pragma unroll
            for (int off = 1; off < 16; off <<= 1) {
                s1 += __shfl_xor(s1, off, 64);
                s2 += __shfl_xor(s2, off, 64);
            }
            float mm = s1 / (float)FO;
            float var = s2 / (float)FO - mm * mm;
            var = var > 0.f ? var : 0.f;
            mu[rr] = mm;
            rs[rr] = rsqrtf(var + LN_EPS);
        }
        #pragma unroll
        for (int nt = 0; nt < NT; ++nt) {
            int n0 = nt * 16 + m;
            float g = ldf(gam, n0, isF);
            float be = ldf(bet, n0, isF);
            #pragma unroll
            for (int rr = 0; rr < 4; ++rr) {
                int row = wrow0 + r * 16 + q * 4 + rr;
                if (row < M) {
                    float y = (acc[r][nt][rr] - mu[rr]) * rs[rr] * g + be;
                    y = y > 0.f ? y : 0.f;
                    H[(size_t)row * FO + n0] = f2b(y);
                }
            }
        }
    }
}

// ---------------- layer-3 GEMM (no epilogue): T3 = H2 @ [Wl2;Wr2]^T, K=128, 128 outs ----------------
// cols 0..63 = Y3 (to be aggregated), 64..127 = S3 (self term).
__global__ __launch_bounds__(256, 2) void k_gemm3(
    const ushort_t* __restrict__ X,   // H2 [M,128]
    const ushort_t* __restrict__ Wb,  // [128][128] bf16 (stacked Wl2,Wr2)
    ushort_t* __restrict__ T,         // [M,128] bf16
    int M) {
    constexpr int NT = 8;
    constexpr int R = 2;
    int lane = threadIdx.x & 63;
    int wid = threadIdx.x >> 6;
    int wrow0 = (blockIdx.x * 4 + wid) * (R * 16);
    if (wrow0 >= M) return;
    int m = lane & 15;
    int q = lane >> 4;

    int arow[R];
    #pragma unroll
    for (int r = 0; r < R; ++r) {
        int ar = wrow0 + r * 16 + m;
        arow[r] = (ar < M) ? ar : (M - 1);
    }

    f32x4 acc[R][NT];
    #pragma unroll
    for (int r = 0; r < R; ++r)
        #pragma unroll
        for (int nt = 0; nt < NT; ++nt) acc[r][nt] = (f32x4){0.f, 0.f, 0.f, 0.f};

    #pragma unroll
    for (int kk = 0; kk < 4; ++kk) {
        int ko = kk * 32 + q * 8;
        s16x8 a[R];
        #pragma unroll
        for (int r = 0; r < R; ++r)
            a[r] = *(const s16x8*)(X + (size_t)arow[r] * 128 + ko);
        #pragma unroll
        for (int nt = 0; nt < NT; ++nt) {
            s16x8 b = *(const s16x8*)(Wb + (size_t)(nt * 16 + m) * 128 + ko);
            #pragma unroll
            for (int r = 0; r < R; ++r)
                acc[r][nt] = __builtin_amdgcn_mfma_f32_16x16x32_bf16(a[r], b, acc[r][nt], 0, 0, 0);
        }
    }

    #pragma unroll
    for (int r = 0; r < R; ++r)
        #pragma unroll
        for (int nt = 0; nt < NT; ++nt) {
            int n0 = nt * 16 + m;
            #pragma unroll
            for (int rr = 0; rr < 4; ++rr) {
                int row = wrow0 + r * 16 + q * 4 + rr;
                if (row < M) T[(size_t)row * 128 + n0] = f2b(acc[r][nt][rr]);
            }
        }
}

// ---------------- layer-3 aggregate + self + bias + LN + ReLU ----------------
// one wave per node; slot qn in {0..3}, fo in {0..15} handles feats 4*fo..4*fo+3 (uint2 = 8B).
__global__ __launch_bounds__(256) void k_agg3(
    const ushort_t* __restrict__ T,  // [N,128]: Y3 | S3
    const int* __restrict__ rowptr, const int* __restrict__ col,
    const void* bl, const void* gam, const void* bet, const int* __restrict__ flags,
    ushort_t* __restrict__ H, int N) {  // H: [N,64]
    int i = blockIdx.x * 4 + (threadIdx.x >> 6);
    if (i >= N) return;
    int l = threadIdx.x & 63;
    int qn = l >> 4;
    int fo = l & 15;
    int isF = flags[0];
    const uint2* T2 = (const uint2*)T;  // row = 32 uint2 (Y3 = first 16, S3 = next 16)
    int s = rowptr[i], e = rowptr[i + 1];
    float al[2] = {0.f, 0.f};  // low bf16 of the 2 uints
    float ah[2] = {0.f, 0.f};  // high bf16
    int p = s + qn;
    for (; p + 4 < e; p += 8) {
        int j0 = col[p], j1 = col[p + 4];
        uint2 u0 = T2[(size_t)j0 * 32 + fo];
        uint2 u1 = T2[(size_t)j1 * 32 + fo];
        unsigned w0[2] = {u0.x, u0.y};
        unsigned w1[2] = {u1.x, u1.y};
        #pragma unroll
        for (int k = 0; k < 2; ++k) {
            al[k] += __uint_as_float(w0[k] << 16) + __uint_as_float(w1[k] << 16);
            ah[k] += __uint_as_float(w0[k] & 0xFFFF0000u) + __uint_as_float(w1[k] & 0xFFFF0000u);
        }
    }
    for (; p < e; p += 4) {
        int j = col[p];
        uint2 u = T2[(size_t)j * 32 + fo];
        unsigned w0[2] = {u.x, u.y};
        #pragma unroll
        for (int k = 0; k < 2; ++k) {
            al[k] += __uint_as_float(w0[k] << 16);
            ah[k] += __uint_as_float(w0[k] & 0xFFFF0000u);
        }
    }
    #pragma unroll
    for (int k = 0; k < 2; ++k) {
        al[k] += __shfl_xor(al[k], 16, 64);
        al[k] += __shfl_xor(al[k], 32, 64);
        ah[k] += __shfl_xor(ah[k], 16, 64);
        ah[k] += __shfl_xor(ah[k], 32, 64);
    }
    // all lanes now hold neighbor sums for feats 4*fo..4*fo+3
    int d = e - s;
    float inv = 1.f / (float)(d > 0 ? d : 1);
    uint2 su = T2[(size_t)i * 32 + 16 + fo];  // S3 self
    float v0 = al[0] * inv + __uint_as_float(su.x << 16) + ldf(bl, 4 * fo + 0, isF);
    float v1 = ah[0] * inv + __uint_as_float(su.x & 0xFFFF0000u) + ldf(bl, 4 * fo + 1, isF);
    float v2 = al[1] * inv + __uint_as_float(su.y << 16) + ldf(bl, 4 * fo + 2, isF);
    float v3 = ah[1] * inv + __uint_as_float(su.y & 0xFFFF0000u) + ldf(bl, 4 * fo + 3, isF);
    // LN across 64 feats = 16 lanes x 4
    float s1 = v0 + v1 + v2 + v3;
    float s2 = v0 * v0 + v1 * v1 + v2 * v2 + v3 * v3;
    #pragma unroll
    for (int off = 1; off < 16; off <<= 1) {
        s1 += __shfl_xor(s1, off, 64);
        s2 += __shfl_xor(s2, off, 64);
    }
    float mu = s1 / 64.f;
    float var = s2 / 64.f - mu * mu;
    var = var > 0.f ? var : 0.f;
    float rs = rsqrtf(var + LN_EPS);
    if (qn == 0) {
        float y0 = (v0 - mu) * rs * ldf(gam, 4 * fo + 0, isF) + ldf(bet, 4 * fo + 0, isF);
        float y1 = (v1 - mu) * rs * ldf(gam, 4 * fo + 1, isF) + ldf(bet, 4 * fo + 1, isF);
        float y2 = (v2 - mu) * rs * ldf(gam, 4 * fo + 2, isF) + ldf(bet, 4 * fo + 2, isF);
        float y3 = (v3 - mu) * rs * ldf(gam, 4 * fo + 3, isF) + ldf(bet, 4 * fo + 3, isF);
        y0 = y0 > 0.f ? y0 : 0.f;
        y1 = y1 > 0.f ? y1 : 0.f;
        y2 = y2 > 0.f ? y2 : 0.f;
        y3 = y3 > 0.f ? y3 : 0.f;
        uint2 o;
        o.x = f2b2(y0, y1);
        o.y = f2b2(y2, y3);
        ((uint2*)H)[(size_t)i * 16 + fo] = o;
    }
}

// ---------------- pooling: Z[64][128]: cols 0..63 sum, 64..127 max ----------------
__global__ __launch_bounds__(256) void k_pool(
    const ushort_t* __restrict__ H,  // [N,64], post-ReLU (>=0)
    const int* __restrict__ bounds, float* __restrict__ Z, int N) {
    int g = blockIdx.x >> 4;
    int chunk = blockIdx.x & 15;
    int lane = threadIdx.x & 31;   // feature pair
    int sub = threadIdx.x >> 5;    // 0..7
    int strm = chunk * 8 + sub;    // 0..127
    int s = bounds[g], e = bounds[g + 1];
    s = s < 0 ? 0 : (s > N ? N : s);
    e = e < s ? s : (e > N ? N : e);
    const unsigned* H2 = (const unsigned*)H;
    float sl = 0.f, sh = 0.f, ml = 0.f, mh = 0.f;
    for (int i = s + strm; i < e; i += 128) {
        unsigned u = H2[(size_t)i * 32 + lane];
        float vl = __uint_as_float(u << 16);
        float vh = __uint_as_float(u & 0xFFFF0000u);
        sl += vl; sh += vh;
        ml = ml > vl ? ml : vl;
        mh = mh > vh ? mh : vh;
    }
    int f0 = lane * 2;
    atomicAdd(&Z[g * 128 + f0], sl);
    atomicAdd(&Z[g * 128 + f0 + 1], sh);
    atomicMax((int*)&Z[g * 128 + 64 + f0], __float_as_int(ml));
    atomicMax((int*)&Z[g * 128 + 64 + f0 + 1], __float_as_int(mh));
}

// ---------------- final MLP; output dtype follows flags[0] ----------------
__global__ void k_mlp(const float* __restrict__ Z, const int* __restrict__ bounds,
                      const void* cW1, const void* cb1, const void* cW2, const void* cb2,
                      const int* __restrict__ flags, void* __restrict__ out) {
    int g = blockIdx.x;
    int f = threadIdx.x;  // 0..127
    int isF = flags[0];
    __shared__ float z[128];
    __shared__ float hid[128];
    __shared__ float r0[2], r1[2];
    int cnt = bounds[g + 1] - bounds[g];
    float c = (float)(cnt > 0 ? cnt : 1);
    float zv = Z[g * 128 + f];
    if (f < 64) zv /= c;
    z[f] = zv;
    __syncthreads();
    float acc = ldf(cb1, f, isF);
    #pragma unroll 8
    for (int k = 0; k < 128; ++k) acc += z[k] * ldf(cW1, f * 128 + k, isF);
    acc = acc > 0.f ? acc : 0.f;
    hid[f] = acc;
    __syncthreads();
    float p0 = hid[f] * ldf(cW2, f, isF);
    float p1 = hid[f] * ldf(cW2, 128 + f, isF);
    #pragma unroll
    for (int off = 32; off > 0; off >>= 1) {
        p0 += __shfl_xor(p0, off, 64);
        p1 += __shfl_xor(p1, off, 64);
    }
    int w = f >> 6;
    if ((f & 63) == 0) { r0[w] = p0; r1[w] = p1; }
    __syncthreads();
    if (f == 0) {
        float v0 = r0[0] + r0[1] + ldf(cb2, 0, isF);
        float v1 = r1[0] + r1[1] + ldf(cb2, 1, isF);
        if (isF) {
            ((float*)out)[g * 2 + 0] = v0;
            ((float*)out)[g * 2 + 1] = v1;
        } else {
            ((ushort_t*)out)[g * 2 + 0] = f2b(v0);
            ((ushort_t*)out)[g * 2 + 1] = f2b(v1);
        }
    }
}

// ---------------- launch ----------------
extern "C" void kernel_launch(void* const* d_in, const int* in_sizes, int n_in,
                              void* d_out, int out_size, void* d_ws, size_t ws_size,
                              hipStream_t stream) {
    const void* x = d_in[0];
    const void* ei = d_in[1];
    const void* batch = d_in[2];
    const void* Wl0 = d_in[3];
    const void* bl0 = d_in[4];
    const void* Wr0 = d_in[5];
    const void* g0 = d_in[6];
    const void* be0 = d_in[7];
    const void* Wl1 = d_in[8];
    const void* bl1 = d_in[9];
    const void* Wr1 = d_in[10];
    const void* g1 = d_in[11];
    const void* be1 = d_in[12];
    const void* Wl2 = d_in[13];
    const void* bl2 = d_in[14];
    const void* Wr2 = d_in[15];
    const void* g2 = d_in[16];
    const void* be2 = d_in[17];
    const void* cW1 = d_in[18];
    const void* cb1 = d_in[19];
    const void* cW2 = d_in[20];
    const void* cb2 = d_in[21];

    const int N = in_sizes[0] / 128;  // 50000
    const int E = in_sizes[1] / 2;    // 600000
    const int G = 64;

    // workspace carve-up (256B aligned slots)
    char* w = (char*)d_ws;
    size_t o = 0;
    auto take = [&](size_t bytes) -> void* {
        void* p = w + o;
        o = (o + bytes + 255) & ~(size_t)255;
        return p;
    };
    int nb1 = (N + 255) / 256;  // scan phase-1 blocks
    int* flags  = (int*)take(4 * 4);
    int* rowptr = (int*)take((size_t)(N + 1) * 4);
    int* cursor = (int*)take((size_t)N * 4);
    int* deg    = (int*)take((size_t)N * 4);
    int* bsum   = (int*)take((size_t)nb1 * 4);
    int* boff   = (int*)take((size_t)nb1 * 4);
    int* col    = (int*)take((size_t)E * 4);
    int* bounds = (int*)take((size_t)(G + 1) * 4);
    float* Z    = (float*)take((size_t)G * 128 * 4);
    ushort_t* Wb0 = (ushort_t*)take((size_t)128 * 256 * 2);
    ushort_t* Wb1 = (ushort_t*)take((size_t)128 * 256 * 2);
    ushort_t* Wb2 = (ushort_t*)take((size_t)128 * 128 * 2);
    ushort_t* AGG = (ushort_t*)take((size_t)N * 128 * 2);
    ushort_t* H1  = (ushort_t*)take((size_t)N * 128 * 2);
    ushort_t* H2  = (ushort_t*)take((size_t)N * 128 * 2);
    ushort_t* XB  = H2;   // x-as-bf16 overlays H2 (dead before H2 written)
    ushort_t* T3  = AGG;  // layer-3 GEMM out overlays AGG (dead after layer-2 gemm)
    ushort_t* H3  = H1;   // [N,64] reuses H1
    if (o > ws_size) return;

    int eb = (E + 255) / 256;
    int xb = (N * 128 / 4 + 255) / 256;
    int wb = (2 * 32768 + 16384 + 255) / 256;
    k_detect_zero<<<nb1, 256, 0, stream>>>(Wl0, ei, flags, deg, Z, N);
    k_prep<<<xb + eb + wb, 256, 0, stream>>>(x, XB, N * 128 / 4, xb,
                                             ei, E, N, deg, eb,
                                             Wl0, Wr0, Wl1, Wr1, Wl2, Wr2,
                                             Wb0, Wb1, Wb2, flags);
    k_scan1<<<nb1, 256, 0, stream>>>(deg, N, rowptr, bsum);
    k_scan2<<<1, 256, 0, stream>>>(bsum, nb1, boff, rowptr + N, batch, N, G, flags, bounds);
    k_scan3<<<nb1, 256, 0, stream>>>(rowptr, boff, cursor, N);
    k_fill<<<eb, 256, 0, stream>>>(ei, E, N, flags, cursor, col);

    int gb = (N + 127) / 128;  // gemm blocks (4 waves x 32 rows)
    int ab = (N + 3) / 4;      // agg blocks (4 waves = 4 nodes each)

    // layer 0: XB -> H1
    k_agg<<<ab, 256, 0, stream>>>(XB, rowptr, col, AGG, N);
    k_gemm_ln<128><<<gb, 256, 0, stream>>>(AGG, XB, Wb0, bl0, g0, be0, flags, H1, N);
    // layer 1: H1 -> H2 (overwrites XB; XB dead)
    k_agg<<<ab, 256, 0, stream>>>(H1, rowptr, col, AGG, N);
    k_gemm_ln<128><<<gb, 256, 0, stream>>>(AGG, H1, Wb1, bl1, g1, be1, flags, H2, N);
    // layer 2 (reordered): T3 = H2 @ [Wl2;Wr2]^T, then aggregate Y3 + epilogue
    k_gemm3<<<gb, 256, 0, stream>>>(H2, Wb2, T3, N);
    k_agg3<<<ab, 256, 0, stream>>>(T3, rowptr, col, bl2, g2, be2, flags, H3, N);

    k_pool<<<G * 16, 256, 0, stream>>>(H3, bounds, Z, N);
    k_mlp<<<G, 128, 0, stream>>>(Z, bounds, cW1, cb1, cW2, cb2, flags, d_out);
}

// Round 14
// 371.630 us; speedup vs baseline: 1.0148x; 1.0148x over previous
//
#include <hip/hip_runtime.h>

typedef unsigned short ushort_t;
typedef short s16x8 __attribute__((ext_vector_type(8)));
typedef float f32x4 __attribute__((ext_vector_type(4)));

#define LN_EPS 1e-5f

// ---- bf16 <-> f32 helpers ----
__device__ __forceinline__ float b2f(ushort_t u) {
    return __uint_as_float(((unsigned)u) << 16);
}
__device__ __forceinline__ ushort_t f2b(float f) {
    unsigned b = __float_as_uint(f);
    b += 0x7FFFu + ((b >> 16) & 1u);  // round-to-nearest-even
    return (ushort_t)(b >> 16);
}
__device__ __forceinline__ unsigned f2b2(float lo, float hi) {  // pack two bf16
    return (unsigned)f2b(lo) | ((unsigned)f2b(hi) << 16);
}
// dtype-flexible load: isF ? fp32 : bf16
__device__ __forceinline__ float ldf(const void* p, size_t i, int isF) {
    return isF ? ((const float*)p)[i] : b2f(((const ushort_t*)p)[i]);
}

// harness-compat symbol (unused)
__global__ void GraphSAGE_36026185678961_kernel() {}

// ---------------- dtype detect (block 0) + zero-init deg, Z ----------------
__global__ void k_detect_zero(const void* w0, const void* ei, int* __restrict__ flags,
                              int* __restrict__ deg, float* __restrict__ Z, int N) {
    int i = blockIdx.x * blockDim.x + threadIdx.x;
    if (i < N) deg[i] = 0;
    if (i < 64 * 128) Z[i] = 0.f;
    if (blockIdx.x == 0 && threadIdx.x < 64) {
        int t = threadIdx.x;
        const ushort_t* u = (const ushort_t*)w0;
        int pass = 0;
        #pragma unroll
        for (int k = 0; k < 4; ++k) {
            ushort_t v = u[t * 4 + k];
            int ex = (v >> 7) & 0xFF;
            if (ex == 0 || (ex >= 0x60 && ex <= 0x7E)) pass++;
        }
        const unsigned* w = (const unsigned*)ei;
        int nz = (w[2 * t + 1] != 0u) ? 1 : 0;
        #pragma unroll
        for (int off = 32; off; off >>= 1) {
            pass += __shfl_down(pass, off, 64);
            nz += __shfl_down(nz, off, 64);
        }
        if (t == 0) {
            flags[0] = (pass < 205) ? 1 : 0;
            flags[1] = (nz == 0) ? 1 : 0;
        }
    }
}

// ---------------- fused prep: xconv | degree histogram | weight repack ----------------
__global__ void k_prep(const void* X, ushort_t* __restrict__ XB, int total4, int xb,
                       const void* ei, int E, int N, int* __restrict__ deg, int eb,
                       const void* Wl0, const void* Wr0, const void* Wl1, const void* Wr1,
                       const void* Wl2, const void* Wr2,
                       ushort_t* __restrict__ Wb0, ushort_t* __restrict__ Wb1,
                       ushort_t* __restrict__ Wb2,
                       const int* __restrict__ flags) {
    int b = blockIdx.x;
    if (b < xb) {
        int idx = b * 256 + threadIdx.x;
        if (idx >= total4) return;
        if (flags[0]) {
            float4 v = ((const float4*)X)[idx];
            ushort4 o;
            o.x = f2b(v.x); o.y = f2b(v.y); o.z = f2b(v.z); o.w = f2b(v.w);
            ((ushort4*)XB)[idx] = o;
        } else {
            ((ushort4*)XB)[idx] = ((const ushort4*)X)[idx];
        }
    } else if (b < xb + eb) {
        int e = (b - xb) * 256 + threadIdx.x;
        if (e >= E) return;
        int d = flags[1] ? (int)((const long long*)ei)[E + e] : ((const int*)ei)[E + e];
        if ((unsigned)d < (unsigned)N) atomicAdd(&deg[d], 1);
    } else {
        int t = (b - xb - eb) * 256 + threadIdx.x;
        int isF = flags[0];
        if (t < 2 * 32768) {  // layers 0,1: [f][256]
            const void* Wl = (t < 32768) ? Wl0 : Wl1;
            const void* Wr = (t < 32768) ? Wr0 : Wr1;
            ushort_t* Wb = (t < 32768) ? Wb0 : Wb1;
            int base = t & 32767;
            int f = base >> 8, k = base & 255;
            if (isF) {
                float v = (k < 128) ? ((const float*)Wl)[f * 128 + k]
                                    : ((const float*)Wr)[f * 128 + (k - 128)];
                Wb[base] = f2b(v);
            } else {
                Wb[base] = ((const ushort_t*)((k < 128) ? Wl : Wr))[f * 128 + (k & 127)];
            }
        } else if (t < 2 * 32768 + 16384) {  // layer 2: [128][128], rows 0..63 Wl2, 64..127 Wr2
            int base = t - 2 * 32768;
            int f = base >> 7, k = base & 127;
            const void* W = (f < 64) ? Wl2 : Wr2;
            int fr = f & 63;
            Wb2[base] = isF ? f2b(((const float*)W)[fr * 128 + k])
                            : ((const ushort_t*)W)[fr * 128 + k];
        }
    }
}

// hierarchical scan, phase 1
__global__ void k_scan1(const int* __restrict__ deg, int N,
                        int* __restrict__ rowptr, int* __restrict__ bsum) {
    __shared__ int wsum[4];
    __shared__ int wpre[4];
    int tid = threadIdx.x;
    int lane = tid & 63;
    int w = tid >> 6;
    int i = blockIdx.x * 256 + tid;
    int v = (i < N) ? deg[i] : 0;
    int x = v;
    #pragma unroll
    for (int off = 1; off < 64; off <<= 1) {
        int t = __shfl_up(x, off, 64);
        if (lane >= off) x += t;
    }
    if (lane == 63) wsum[w] = x;
    __syncthreads();
    if (tid == 0) {
        int a = wsum[0]; wpre[0] = a;
        a += wsum[1]; wpre[1] = a;
        a += wsum[2]; wpre[2] = a;
        a += wsum[3]; wpre[3] = a;
    }
    __syncthreads();
    int woff = (w == 0) ? 0 : wpre[w - 1];
    if (i < N) rowptr[i] = woff + x - v;
    if (tid == 0) bsum[blockIdx.x] = wpre[3];
}

// phase 2: scan of block sums + graph bounds (fused)
__global__ void k_scan2(const int* __restrict__ bsum, int nb,
                        int* __restrict__ boff, int* __restrict__ rowptrN,
                        const void* batch, int N, int G, const int* __restrict__ flags,
                        int* __restrict__ bounds) {
    __shared__ int wsum[4];
    __shared__ int wpre[4];
    int tid = threadIdx.x;
    int lane = tid & 63;
    int w = tid >> 6;
    int run = 0;
    for (int base = 0; base < nb; base += 256) {
        int i = base + tid;
        int v = (i < nb) ? bsum[i] : 0;
        int x = v;
        #pragma unroll
        for (int off = 1; off < 64; off <<= 1) {
            int t = __shfl_up(x, off, 64);
            if (lane >= off) x += t;
        }
        if (lane == 63) wsum[w] = x;
        __syncthreads();
        if (tid == 0) {
            int a = wsum[0]; wpre[0] = a;
            a += wsum[1]; wpre[1] = a;
            a += wsum[2]; wpre[2] = a;
            a += wsum[3]; wpre[3] = a;
        }
        __syncthreads();
        int woff = (w == 0) ? 0 : wpre[w - 1];
        if (i < nb) boff[i] = run + woff + x - v;
        int tot = wpre[3];
        __syncthreads();
        run += tot;
    }
    if (tid == 0) *rowptrN = run;
    if (tid <= G) {
        int isL = flags[1];
        int lo = 0, hi = N;
        while (lo < hi) {
            int mid = (lo + hi) >> 1;
            int bv = isL ? (int)((const long long*)batch)[mid] : ((const int*)batch)[mid];
            if (bv < tid) lo = mid + 1; else hi = mid;
        }
        bounds[tid] = lo;
    }
}

// phase 3
__global__ void k_scan3(int* __restrict__ rowptr, const int* __restrict__ boff,
                        int* __restrict__ cursor, int N) {
    int i = blockIdx.x * 256 + threadIdx.x;
    if (i < N) {
        int r = rowptr[i] + boff[i >> 8];
        rowptr[i] = r;
        cursor[i] = r;
    }
}

// CSR fill (reads edge_index directly)
__global__ void k_fill(const void* ei, int E, int N, const int* __restrict__ flags,
                       int* __restrict__ cursor, int* __restrict__ col) {
    int e = blockIdx.x * blockDim.x + threadIdx.x;
    if (e >= E) return;
    int s, d;
    if (flags[1]) {
        const long long* p = (const long long*)ei;
        s = (int)p[e];
        d = (int)p[E + e];
    } else {
        const int* p = (const int*)ei;
        s = p[e];
        d = p[E + e];
    }
    if ((unsigned)d < (unsigned)N) {
        int p = atomicAdd(&cursor[d], 1);
        if ((unsigned)p < (unsigned)E) col[p] = ((unsigned)s < (unsigned)N) ? s : 0;
    }
}

// ---------------- mean aggregation: AGG[i] = mean_{j in N(i)} X[j]  (bf16, 128-wide) ----------------
// one wave per node; slot qn (16 lanes x uint4 = one row) handles neighbors qn, qn+4, ...
// main loop: 3 gathers in flight = 12 neighbors/iter (covers mean degree in ONE round).
__global__ __launch_bounds__(256) void k_agg(
    const ushort_t* __restrict__ X, const int* __restrict__ rowptr,
    const int* __restrict__ col, ushort_t* __restrict__ AGG, int N) {
    int i = blockIdx.x * 4 + (threadIdx.x >> 6);
    if (i >= N) return;
    int l = threadIdx.x & 63;
    int qn = l >> 4;   // neighbor slot 0..3
    int fo = l & 15;   // feature octet
    const uint4* X8 = (const uint4*)X;  // row = 16 uint4 groups
    int s = rowptr[i], e = rowptr[i + 1];
    float al[4] = {0.f, 0.f, 0.f, 0.f};
    float ah[4] = {0.f, 0.f, 0.f, 0.f};
    int p = s + qn;
    for (; p + 8 < e; p += 12) {  // 12 neighbors per wave-iter, 3 loads/lane in flight
        int j0 = col[p], j1 = col[p + 4], j2 = col[p + 8];
        uint4 u0 = X8[(size_t)j0 * 16 + fo];
        uint4 u1 = X8[(size_t)j1 * 16 + fo];
        uint4 u2 = X8[(size_t)j2 * 16 + fo];
        unsigned w0[4] = {u0.x, u0.y, u0.z, u0.w};
        unsigned w1[4] = {u1.x, u1.y, u1.z, u1.w};
        unsigned w2[4] = {u2.x, u2.y, u2.z, u2.w};
        #pragma unroll
        for (int k = 0; k < 4; ++k) {
            al[k] += __uint_as_float(w0[k] << 16) + __uint_as_float(w1[k] << 16)
                   + __uint_as_float(w2[k] << 16);
            ah[k] += __uint_as_float(w0[k] & 0xFFFF0000u) + __uint_as_float(w1[k] & 0xFFFF0000u)
                   + __uint_as_float(w2[k] & 0xFFFF0000u);
        }
    }
    if (p + 4 < e) {  // 2-deep tail (8 neighbors)
        int j0 = col[p], j1 = col[p + 4];
        uint4 u0 = X8[(size_t)j0 * 16 + fo];
        uint4 u1 = X8[(size_t)j1 * 16 + fo];
        unsigned w0[4] = {u0.x, u0.y, u0.z, u0.w};
        unsigned w1[4] = {u1.x, u1.y, u1.z, u1.w};
        #pragma unroll
        for (int k = 0; k < 4; ++k) {
            al[k] += __uint_as_float(w0[k] << 16) + __uint_as_float(w1[k] << 16);
            ah[k] += __uint_as_float(w0[k] & 0xFFFF0000u) + __uint_as_float(w1[k] & 0xFFFF0000u);
        }
        p += 8;
    }
    if (p < e) {  // final single
        int j = col[p];
        uint4 u = X8[(size_t)j * 16 + fo];
        unsigned w0[4] = {u.x, u.y, u.z, u.w};
        #pragma unroll
        for (int k = 0; k < 4; ++k) {
            al[k] += __uint_as_float(w0[k] << 16);
            ah[k] += __uint_as_float(w0[k] & 0xFFFF0000u);
        }
    }
    #pragma unroll
    for (int k = 0; k < 4; ++k) {
        al[k] += __shfl_xor(al[k], 16, 64);
        al[k] += __shfl_xor(al[k], 32, 64);
        ah[k] += __shfl_xor(ah[k], 16, 64);
        ah[k] += __shfl_xor(ah[k], 32, 64);
    }
    if (qn == 0) {
        int d = e - s;
        float inv = 1.f / (float)(d > 0 ? d : 1);
        uint4 o;
        o.x = f2b2(al[0] * inv, ah[0] * inv);
        o.y = f2b2(al[1] * inv, ah[1] * inv);
        o.z = f2b2(al[2] * inv, ah[2] * inv);
        o.w = f2b2(al[3] * inv, ah[3] * inv);
        ((uint4*)AGG)[(size_t)i * 16 + fo] = o;
    }
}

// ---------------- fused MFMA GEMM + bias + LayerNorm + ReLU (layers 0,1) ----------------
template <int FO>
__global__ __launch_bounds__(256, 2) void k_gemm_ln(
    const ushort_t* __restrict__ AGG, const ushort_t* __restrict__ X,
    const ushort_t* __restrict__ Wb,  // [FO][256] bf16
    const void* bl, const void* gam, const void* bet,
    const int* __restrict__ flags,
    ushort_t* __restrict__ H, int M) {
    constexpr int NT = FO / 16;
    constexpr int R = 2;
    int lane = threadIdx.x & 63;
    int wid = threadIdx.x >> 6;
    int wrow0 = (blockIdx.x * 4 + wid) * (R * 16);
    if (wrow0 >= M) return;
    int isF = flags[0];
    int m = lane & 15;
    int q = lane >> 4;

    int arow[R];
    #pragma unroll
    for (int r = 0; r < R; ++r) {
        int ar = wrow0 + r * 16 + m;
        arow[r] = (ar < M) ? ar : (M - 1);
    }

    f32x4 acc[R][NT];
    #pragma unroll
    for (int r = 0; r < R; ++r)
        #pragma unroll
        for (int nt = 0; nt < NT; ++nt) acc[r][nt] = (f32x4){0.f, 0.f, 0.f, 0.f};

    #pragma unroll
    for (int kk = 0; kk < 8; ++kk) {
        const ushort_t* base = (kk < 4) ? AGG : X;
        int ko = (kk & 3) * 32 + q * 8;
        s16x8 a[R];
        #pragma unroll
        for (int r = 0; r < R; ++r)
            a[r] = *(const s16x8*)(base + (size_t)arow[r] * 128 + ko);
        #pragma unroll
        for (int nt = 0; nt < NT; ++nt) {
            s16x8 b = *(const s16x8*)(Wb + (size_t)(nt * 16 + m) * 256 + kk * 32 + q * 8);
            #pragma unroll
            for (int r = 0; r < R; ++r)
                acc[r][nt] = __builtin_amdgcn_mfma_f32_16x16x32_bf16(a[r], b, acc[r][nt], 0, 0, 0);
        }
    }

    #pragma unroll
    for (int r = 0; r < R; ++r) {
        #pragma unroll
        for (int nt = 0; nt < NT; ++nt) {
            float bv = ldf(bl, nt * 16 + m, isF);
            #pragma unroll
            for (int rr = 0; rr < 4; ++rr) acc[r][nt][rr] += bv;
        }
        float mu[4], rs[4];
        #pragma unroll
        for (int rr = 0; rr < 4; ++rr) {
            float s1 = 0.f, s2 = 0.f;
            #pragma unroll
            for (int nt = 0; nt < NT; ++nt) {
                float v = acc[r][nt][rr];
                s1 += v;
                s2 += v * v;
            }
            #pragma unroll
            for (int off = 1; off < 16; off <<= 1) {
                s1 += __shfl_xor(s1, off, 64);
                s2 += __shfl_xor(s2, off, 64);
            }
            float mm = s1 / (float)FO;
            float var = s2 / (float)FO - mm * mm;
            var = var > 0.f ? var : 0.f;
            mu[rr] = mm;
            rs[rr] = rsqrtf(var + LN_EPS);
        }
        #pragma unroll
        for (int nt = 0; nt < NT; ++nt) {
            int n0 = nt * 16 + m;
            float g = ldf(gam, n0, isF);
            float be = ldf(bet, n0, isF);
            #pragma unroll
            for (int rr = 0; rr < 4; ++rr) {
                int row = wrow0 + r * 16 + q * 4 + rr;
                if (row < M) {
                    float y = (acc[r][nt][rr] - mu[rr]) * rs[rr] * g + be;
                    y = y > 0.f ? y : 0.f;
                    H[(size_t)row * FO + n0] = f2b(y);
                }
            }
        }
    }
}

// ---------------- layer-3 GEMM (no epilogue): T3 = H2 @ [Wl2;Wr2]^T ----------------
__global__ __launch_bounds__(256, 2) void k_gemm3(
    const ushort_t* __restrict__ X,   // H2 [M,128]
    const ushort_t* __restrict__ Wb,  // [128][128] bf16 (stacked Wl2,Wr2)
    ushort_t* __restrict__ T,         // [M,128] bf16
    int M) {
    constexpr int NT = 8;
    constexpr int R = 2;
    int lane = threadIdx.x & 63;
    int wid = threadIdx.x >> 6;
    int wrow0 = (blockIdx.x * 4 + wid) * (R * 16);
    if (wrow0 >= M) return;
    int m = lane & 15;
    int q = lane >> 4;

    int arow[R];
    #pragma unroll
    for (int r = 0; r < R; ++r) {
        int ar = wrow0 + r * 16 + m;
        arow[r] = (ar < M) ? ar : (M - 1);
    }

    f32x4 acc[R][NT];
    #pragma unroll
    for (int r = 0; r < R; ++r)
        #pragma unroll
        for (int nt = 0; nt < NT; ++nt) acc[r][nt] = (f32x4){0.f, 0.f, 0.f, 0.f};

    #pragma unroll
    for (int kk = 0; kk < 4; ++kk) {
        int ko = kk * 32 + q * 8;
        s16x8 a[R];
        #pragma unroll
        for (int r = 0; r < R; ++r)
            a[r] = *(const s16x8*)(X + (size_t)arow[r] * 128 + ko);
        #pragma unroll
        for (int nt = 0; nt < NT; ++nt) {
            s16x8 b = *(const s16x8*)(Wb + (size_t)(nt * 16 + m) * 128 + ko);
            #pragma unroll
            for (int r = 0; r < R; ++r)
                acc[r][nt] = __builtin_amdgcn_mfma_f32_16x16x32_bf16(a[r], b, acc[r][nt], 0, 0, 0);
        }
    }

    #pragma unroll
    for (int r = 0; r < R; ++r)
        #pragma unroll
        for (int nt = 0; nt < NT; ++nt) {
            int n0 = nt * 16 + m;
            #pragma unroll
            for (int rr = 0; rr < 4; ++rr) {
                int row = wrow0 + r * 16 + q * 4 + rr;
                if (row < M) T[(size_t)row * 128 + n0] = f2b(acc[r][nt][rr]);
            }
        }
}

// ---------------- layer-3 aggregate + self + bias + LN + ReLU ----------------
__global__ __launch_bounds__(256) void k_agg3(
    const ushort_t* __restrict__ T,  // [N,128]: Y3 | S3
    const int* __restrict__ rowptr, const int* __restrict__ col,
    const void* bl, const void* gam, const void* bet, const int* __restrict__ flags,
    ushort_t* __restrict__ H, int N) {  // H: [N,64]
    int i = blockIdx.x * 4 + (threadIdx.x >> 6);
    if (i >= N) return;
    int l = threadIdx.x & 63;
    int qn = l >> 4;
    int fo = l & 15;
    int isF = flags[0];
    const uint2* T2 = (const uint2*)T;  // row = 32 uint2 (Y3 = first 16, S3 = next 16)
    int s = rowptr[i], e = rowptr[i + 1];
    float al[2] = {0.f, 0.f};
    float ah[2] = {0.f, 0.f};
    int p = s + qn;
    for (; p + 8 < e; p += 12) {  // 3 gathers in flight
        int j0 = col[p], j1 = col[p + 4], j2 = col[p + 8];
        uint2 u0 = T2[(size_t)j0 * 32 + fo];
        uint2 u1 = T2[(size_t)j1 * 32 + fo];
        uint2 u2 = T2[(size_t)j2 * 32 + fo];
        unsigned w0[2] = {u0.x, u0.y};
        unsigned w1[2] = {u1.x, u1.y};
        unsigned w2[2] = {u2.x, u2.y};
        #pragma unroll
        for (int k = 0; k < 2; ++k) {
            al[k] += __uint_as_float(w0[k] << 16) + __uint_as_float(w1[k] << 16)
                   + __uint_as_float(w2[k] << 16);
            ah[k] += __uint_as_float(w0[k] & 0xFFFF0000u) + __uint_as_float(w1[k] & 0xFFFF0000u)
                   + __uint_as_float(w2[k] & 0xFFFF0000u);
        }
    }
    if (p + 4 < e) {
        int j0 = col[p], j1 = col[p + 4];
        uint2 u0 = T2[(size_t)j0 * 32 + fo];
        uint2 u1 = T2[(size_t)j1 * 32 + fo];
        unsigned w0[2] = {u0.x, u0.y};
        unsigned w1[2] = {u1.x, u1.y};
        #pragma unroll
        for (int k = 0; k < 2; ++k) {
            al[k] += __uint_as_float(w0[k] << 16) + __uint_as_float(w1[k] << 16);
            ah[k] += __uint_as_float(w0[k] & 0xFFFF0000u) + __uint_as_float(w1[k] & 0xFFFF0000u);
        }
        p += 8;
    }
    if (p < e) {
        int j = col[p];
        uint2 u = T2[(size_t)j * 32 + fo];
        unsigned w0[2] = {u.x, u.y};
        #pragma unroll
        for (int k = 0; k < 2; ++k) {
            al[k] += __uint_as_float(w0[k] << 16);
            ah[k] += __uint_as_float(w0[k] & 0xFFFF0000u);
        }
    }
    #pragma unroll
    for (int k = 0; k < 2; ++k) {
        al[k] += __shfl_xor(al[k], 16, 64);
        al[k] += __shfl_xor(al[k], 32, 64);
        ah[k] += __shfl_xor(ah[k], 16, 64);
        ah[k] += __shfl_xor(ah[k], 32, 64);
    }
    int d = e - s;
    float inv = 1.f / (float)(d > 0 ? d : 1);
    uint2 su = T2[(size_t)i * 32 + 16 + fo];  // S3 self
    float v0 = al[0] * inv + __uint_as_float(su.x << 16) + ldf(bl, 4 * fo + 0, isF);
    float v1 = ah[0] * inv + __uint_as_float(su.x & 0xFFFF0000u) + ldf(bl, 4 * fo + 1, isF);
    float v2 = al[1] * inv + __uint_as_float(su.y << 16) + ldf(bl, 4 * fo + 2, isF);
    float v3 = ah[1] * inv + __uint_as_float(su.y & 0xFFFF0000u) + ldf(bl, 4 * fo + 3, isF);
    float s1 = v0 + v1 + v2 + v3;
    float s2 = v0 * v0 + v1 * v1 + v2 * v2 + v3 * v3;
    #pragma unroll
    for (int off = 1; off < 16; off <<= 1) {
        s1 += __shfl_xor(s1, off, 64);
        s2 += __shfl_xor(s2, off, 64);
    }
    float mu = s1 / 64.f;
    float var = s2 / 64.f - mu * mu;
    var = var > 0.f ? var : 0.f;
    float rs = rsqrtf(var + LN_EPS);
    if (qn == 0) {
        float y0 = (v0 - mu) * rs * ldf(gam, 4 * fo + 0, isF) + ldf(bet, 4 * fo + 0, isF);
        float y1 = (v1 - mu) * rs * ldf(gam, 4 * fo + 1, isF) + ldf(bet, 4 * fo + 1, isF);
        float y2 = (v2 - mu) * rs * ldf(gam, 4 * fo + 2, isF) + ldf(bet, 4 * fo + 2, isF);
        float y3 = (v3 - mu) * rs * ldf(gam, 4 * fo + 3, isF) + ldf(bet, 4 * fo + 3, isF);
        y0 = y0 > 0.f ? y0 : 0.f;
        y1 = y1 > 0.f ? y1 : 0.f;
        y2 = y2 > 0.f ? y2 : 0.f;
        y3 = y3 > 0.f ? y3 : 0.f;
        uint2 o;
        o.x = f2b2(y0, y1);
        o.y = f2b2(y2, y3);
        ((uint2*)H)[(size_t)i * 16 + fo] = o;
    }
}

// ---------------- pooling: Z[64][128]: cols 0..63 sum, 64..127 max ----------------
__global__ __launch_bounds__(256) void k_pool(
    const ushort_t* __restrict__ H,  // [N,64], post-ReLU (>=0)
    const int* __restrict__ bounds, float* __restrict__ Z, int N) {
    int g = blockIdx.x >> 4;
    int chunk = blockIdx.x & 15;
    int lane = threadIdx.x & 31;   // feature pair
    int sub = threadIdx.x >> 5;    // 0..7
    int strm = chunk * 8 + sub;    // 0..127
    int s = bounds[g], e = bounds[g + 1];
    s = s < 0 ? 0 : (s > N ? N : s);
    e = e < s ? s : (e > N ? N : e);
    const unsigned* H2 = (const unsigned*)H;
    float sl = 0.f, sh = 0.f, ml = 0.f, mh = 0.f;
    for (int i = s + strm; i < e; i += 128) {
        unsigned u = H2[(size_t)i * 32 + lane];
        float vl = __uint_as_float(u << 16);
        float vh = __uint_as_float(u & 0xFFFF0000u);
        sl += vl; sh += vh;
        ml = ml > vl ? ml : vl;
        mh = mh > vh ? mh : vh;
    }
    int f0 = lane * 2;
    atomicAdd(&Z[g * 128 + f0], sl);
    atomicAdd(&Z[g * 128 + f0 + 1], sh);
    atomicMax((int*)&Z[g * 128 + 64 + f0], __float_as_int(ml));
    atomicMax((int*)&Z[g * 128 + 64 + f0 + 1], __float_as_int(mh));
}

// ---------------- final MLP; output dtype follows flags[0] ----------------
__global__ void k_mlp(const float* __restrict__ Z, const int* __restrict__ bounds,
                      const void* cW1, const void* cb1, const void* cW2, const void* cb2,
                      const int* __restrict__ flags, void* __restrict__ out) {
    int g = blockIdx.x;
    int f = threadIdx.x;  // 0..127
    int isF = flags[0];
    __shared__ float z[128];
    __shared__ float hid[128];
    __shared__ float r0[2], r1[2];
    int cnt = bounds[g + 1] - bounds[g];
    float c = (float)(cnt > 0 ? cnt : 1);
    float zv = Z[g * 128 + f];
    if (f < 64) zv /= c;
    z[f] = zv;
    __syncthreads();
    float acc = ldf(cb1, f, isF);
    #pragma unroll 8
    for (int k = 0; k < 128; ++k) acc += z[k] * ldf(cW1, f * 128 + k, isF);
    acc = acc > 0.f ? acc : 0.f;
    hid[f] = acc;
    __syncthreads();
    float p0 = hid[f] * ldf(cW2, f, isF);
    float p1 = hid[f] * ldf(cW2, 128 + f, isF);
    #pragma unroll
    for (int off = 32; off > 0; off >>= 1) {
        p0 += __shfl_xor(p0, off, 64);
        p1 += __shfl_xor(p1, off, 64);
    }
    int w = f >> 6;
    if ((f & 63) == 0) { r0[w] = p0; r1[w] = p1; }
    __syncthreads();
    if (f == 0) {
        float v0 = r0[0] + r0[1] + ldf(cb2, 0, isF);
        float v1 = r1[0] + r1[1] + ldf(cb2, 1, isF);
        if (isF) {
            ((float*)out)[g * 2 + 0] = v0;
            ((float*)out)[g * 2 + 1] = v1;
        } else {
            ((ushort_t*)out)[g * 2 + 0] = f2b(v0);
            ((ushort_t*)out)[g * 2 + 1] = f2b(v1);
        }
    }
}

// ---------------- launch ----------------
extern "C" void kernel_launch(void* const* d_in, const int* in_sizes, int n_in,
                              void* d_out, int out_size, void* d_ws, size_t ws_size,
                              hipStream_t stream) {
    const void* x = d_in[0];
    const void* ei = d_in[1];
    const void* batch = d_in[2];
    const void* Wl0 = d_in[3];
    const void* bl0 = d_in[4];
    const void* Wr0 = d_in[5];
    const void* g0 = d_in[6];
    const void* be0 = d_in[7];
    const void* Wl1 = d_in[8];
    const void* bl1 = d_in[9];
    const void* Wr1 = d_in[10];
    const void* g1 = d_in[11];
    const void* be1 = d_in[12];
    const void* Wl2 = d_in[13];
    const void* bl2 = d_in[14];
    const void* Wr2 = d_in[15];
    const void* g2 = d_in[16];
    const void* be2 = d_in[17];
    const void* cW1 = d_in[18];
    const void* cb1 = d_in[19];
    const void* cW2 = d_in[20];
    const void* cb2 = d_in[21];

    const int N = in_sizes[0] / 128;  // 50000
    const int E = in_sizes[1] / 2;    // 600000
    const int G = 64;

    // workspace carve-up (256B aligned slots)
    char* w = (char*)d_ws;
    size_t o = 0;
    auto take = [&](size_t bytes) -> void* {
        void* p = w + o;
        o = (o + bytes + 255) & ~(size_t)255;
        return p;
    };
    int nb1 = (N + 255) / 256;  // scan phase-1 blocks
    int* flags  = (int*)take(4 * 4);
    int* rowptr = (int*)take((size_t)(N + 1) * 4);
    int* cursor = (int*)take((size_t)N * 4);
    int* deg    = (int*)take((size_t)N * 4);
    int* bsum   = (int*)take((size_t)nb1 * 4);
    int* boff   = (int*)take((size_t)nb1 * 4);
    int* col    = (int*)take((size_t)E * 4);
    int* bounds = (int*)take((size_t)(G + 1) * 4);
    float* Z    = (float*)take((size_t)G * 128 * 4);
    ushort_t* Wb0 = (ushort_t*)take((size_t)128 * 256 * 2);
    ushort_t* Wb1 = (ushort_t*)take((size_t)128 * 256 * 2);
    ushort_t* Wb2 = (ushort_t*)take((size_t)128 * 128 * 2);
    ushort_t* AGG = (ushort_t*)take((size_t)N * 128 * 2);
    ushort_t* H1  = (ushort_t*)take((size_t)N * 128 * 2);
    ushort_t* H2  = (ushort_t*)take((size_t)N * 128 * 2);
    ushort_t* XB  = H2;   // x-as-bf16 overlays H2 (dead before H2 written)
    ushort_t* T3  = AGG;  // layer-3 GEMM out overlays AGG (dead after layer-2 gemm)
    ushort_t* H3  = H1;   // [N,64] reuses H1
    if (o > ws_size) return;

    int eb = (E + 255) / 256;
    int xb = (N * 128 / 4 + 255) / 256;
    int wb = (2 * 32768 + 16384 + 255) / 256;
    k_detect_zero<<<nb1, 256, 0, stream>>>(Wl0, ei, flags, deg, Z, N);
    k_prep<<<xb + eb + wb, 256, 0, stream>>>(x, XB, N * 128 / 4, xb,
                                             ei, E, N, deg, eb,
                                             Wl0, Wr0, Wl1, Wr1, Wl2, Wr2,
                                             Wb0, Wb1, Wb2, flags);
    k_scan1<<<nb1, 256, 0, stream>>>(deg, N, rowptr, bsum);
    k_scan2<<<1, 256, 0, stream>>>(bsum, nb1, boff, rowptr + N, batch, N, G, flags, bounds);
    k_scan3<<<nb1, 256, 0, stream>>>(rowptr, boff, cursor, N);
    k_fill<<<eb, 256, 0, stream>>>(ei, E, N, flags, cursor, col);

    int gb = (N + 127) / 128;  // gemm blocks (4 waves x 32 rows)
    int ab = (N + 3) / 4;      // agg blocks (4 waves = 4 nodes each)

    // layer 0: XB -> H1
    k_agg<<<ab, 256, 0, stream>>>(XB, rowptr, col, AGG, N);
    k_gemm_ln<128><<<gb, 256, 0, stream>>>(AGG, XB, Wb0, bl0, g0, be0, flags, H1, N);
    // layer 1: H1 -> H2 (overwrites XB; XB dead)
    k_agg<<<ab, 256, 0, stream>>>(H1, rowptr, col, AGG, N);
    k_gemm_ln<128><<<gb, 256, 0, stream>>>(AGG, H1, Wb1, bl1, g1, be1, flags, H2, N);
    // layer 2 (reordered): T3 = H2 @ [Wl2;Wr2]^T, then aggregate Y3 + epilogue
    k_gemm3<<<gb, 256, 0, stream>>>(H2, Wb2, T3, N);
    k_agg3<<<ab, 256, 0, stream>>>(T3, rowptr, col, bl2, g2, be2, flags, H3, N);

    k_pool<<<G * 16, 256, 0, stream>>>(H3, bounds, Z, N);
    k_mlp<<<G, 128, 0, stream>>>(Z, bounds, cW1, cb1, cW2, cb2, flags, d_out);
}

// Round 15
// 364.019 us; speedup vs baseline: 1.0361x; 1.0209x over previous
//
#include <hip/hip_runtime.h>

typedef unsigned short ushort_t;
typedef short s16x8 __attribute__((ext_vector_type(8)));
typedef float f32x4 __attribute__((ext_vector_type(4)));

#define LN_EPS 1e-5f

// ---- bf16 <-> f32 helpers ----
__device__ __forceinline__ float b2f(ushort_t u) {
    return __uint_as_float(((unsigned)u) << 16);
}
__device__ __forceinline__ ushort_t f2b(float f) {
    unsigned b = __float_as_uint(f);
    b += 0x7FFFu + ((b >> 16) & 1u);  // round-to-nearest-even
    return (ushort_t)(b >> 16);
}
__device__ __forceinline__ unsigned f2b2(float lo, float hi) {  // pack two bf16
    return (unsigned)f2b(lo) | ((unsigned)f2b(hi) << 16);
}
// dtype-flexible load: isF ? fp32 : bf16
__device__ __forceinline__ float ldf(const void* p, size_t i, int isF) {
    return isF ? ((const float*)p)[i] : b2f(((const ushort_t*)p)[i]);
}

// harness-compat symbol (unused)
__global__ void GraphSAGE_36026185678961_kernel() {}

// ---------------- dtype detect (block 0) + zero-init deg, Z ----------------
__global__ void k_detect_zero(const void* w0, const void* ei, int* __restrict__ flags,
                              int* __restrict__ deg, float* __restrict__ Z, int N) {
    int i = blockIdx.x * blockDim.x + threadIdx.x;
    if (i < N) deg[i] = 0;
    if (i < 64 * 128) Z[i] = 0.f;
    if (blockIdx.x == 0 && threadIdx.x < 64) {
        int t = threadIdx.x;
        const ushort_t* u = (const ushort_t*)w0;
        int pass = 0;
        #pragma unroll
        for (int k = 0; k < 4; ++k) {
            ushort_t v = u[t * 4 + k];
            int ex = (v >> 7) & 0xFF;
            if (ex == 0 || (ex >= 0x60 && ex <= 0x7E)) pass++;
        }
        const unsigned* w = (const unsigned*)ei;
        int nz = (w[2 * t + 1] != 0u) ? 1 : 0;
        #pragma unroll
        for (int off = 32; off; off >>= 1) {
            pass += __shfl_down(pass, off, 64);
            nz += __shfl_down(nz, off, 64);
        }
        if (t == 0) {
            flags[0] = (pass < 205) ? 1 : 0;
            flags[1] = (nz == 0) ? 1 : 0;
        }
    }
}

// ---------------- fused prep: xconv | degree histogram | weight repack | cW1 transpose ----------------
__global__ void k_prep(const void* X, ushort_t* __restrict__ XB, int total4, int xb,
                       const void* ei, int E, int N, int* __restrict__ deg, int eb,
                       const void* Wl0, const void* Wr0, const void* Wl1, const void* Wr1,
                       const void* Wl2, const void* Wr2, const void* cW1,
                       ushort_t* __restrict__ Wb0, ushort_t* __restrict__ Wb1,
                       ushort_t* __restrict__ Wb2, float* __restrict__ cW1T,
                       const int* __restrict__ flags) {
    int b = blockIdx.x;
    if (b < xb) {
        int idx = b * 256 + threadIdx.x;
        if (idx >= total4) return;
        if (flags[0]) {
            float4 v = ((const float4*)X)[idx];
            ushort4 o;
            o.x = f2b(v.x); o.y = f2b(v.y); o.z = f2b(v.z); o.w = f2b(v.w);
            ((ushort4*)XB)[idx] = o;
        } else {
            ((ushort4*)XB)[idx] = ((const ushort4*)X)[idx];
        }
    } else if (b < xb + eb) {
        int e = (b - xb) * 256 + threadIdx.x;
        if (e >= E) return;
        int d = flags[1] ? (int)((const long long*)ei)[E + e] : ((const int*)ei)[E + e];
        if ((unsigned)d < (unsigned)N) atomicAdd(&deg[d], 1);
    } else {
        int t = (b - xb - eb) * 256 + threadIdx.x;
        int isF = flags[0];
        if (t < 2 * 32768) {  // layers 0,1: [f][256]
            const void* Wl = (t < 32768) ? Wl0 : Wl1;
            const void* Wr = (t < 32768) ? Wr0 : Wr1;
            ushort_t* Wb = (t < 32768) ? Wb0 : Wb1;
            int base = t & 32767;
            int f = base >> 8, k = base & 255;
            if (isF) {
                float v = (k < 128) ? ((const float*)Wl)[f * 128 + k]
                                    : ((const float*)Wr)[f * 128 + (k - 128)];
                Wb[base] = f2b(v);
            } else {
                Wb[base] = ((const ushort_t*)((k < 128) ? Wl : Wr))[f * 128 + (k & 127)];
            }
        } else if (t < 2 * 32768 + 16384) {  // layer 2: [128][128], rows 0..63 Wl2, 64..127 Wr2
            int base = t - 2 * 32768;
            int f = base >> 7, k = base & 127;
            const void* W = (f < 64) ? Wl2 : Wr2;
            int fr = f & 63;
            Wb2[base] = isF ? f2b(((const float*)W)[fr * 128 + k])
                            : ((const ushort_t*)W)[fr * 128 + k];
        } else if (t < 2 * 32768 + 2 * 16384) {  // cW1 transpose -> fp32 [k][f]
            int base = t - 2 * 32768 - 16384;
            int k = base >> 7, f = base & 127;
            cW1T[base] = ldf(cW1, f * 128 + k, isF);
        }
    }
}

// hierarchical scan, phase 1
__global__ void k_scan1(const int* __restrict__ deg, int N,
                        int* __restrict__ rowptr, int* __restrict__ bsum) {
    __shared__ int wsum[4];
    __shared__ int wpre[4];
    int tid = threadIdx.x;
    int lane = tid & 63;
    int w = tid >> 6;
    int i = blockIdx.x * 256 + tid;
    int v = (i < N) ? deg[i] : 0;
    int x = v;
    #pragma unroll
    for (int off = 1; off < 64; off <<= 1) {
        int t = __shfl_up(x, off, 64);
        if (lane >= off) x += t;
    }
    if (lane == 63) wsum[w] = x;
    __syncthreads();
    if (tid == 0) {
        int a = wsum[0]; wpre[0] = a;
        a += wsum[1]; wpre[1] = a;
        a += wsum[2]; wpre[2] = a;
        a += wsum[3]; wpre[3] = a;
    }
    __syncthreads();
    int woff = (w == 0) ? 0 : wpre[w - 1];
    if (i < N) rowptr[i] = woff + x - v;
    if (tid == 0) bsum[blockIdx.x] = wpre[3];
}

// phase 2: scan of block sums + graph bounds (fused)
__global__ void k_scan2(const int* __restrict__ bsum, int nb,
                        int* __restrict__ boff, int* __restrict__ rowptrN,
                        const void* batch, int N, int G, const int* __restrict__ flags,
                        int* __restrict__ bounds) {
    __shared__ int wsum[4];
    __shared__ int wpre[4];
    int tid = threadIdx.x;
    int lane = tid & 63;
    int w = tid >> 6;
    int run = 0;
    for (int base = 0; base < nb; base += 256) {
        int i = base + tid;
        int v = (i < nb) ? bsum[i] : 0;
        int x = v;
        #pragma unroll
        for (int off = 1; off < 64; off <<= 1) {
            int t = __shfl_up(x, off, 64);
            if (lane >= off) x += t;
        }
        if (lane == 63) wsum[w] = x;
        __syncthreads();
        if (tid == 0) {
            int a = wsum[0]; wpre[0] = a;
            a += wsum[1]; wpre[1] = a;
            a += wsum[2]; wpre[2] = a;
            a += wsum[3]; wpre[3] = a;
        }
        __syncthreads();
        int woff = (w == 0) ? 0 : wpre[w - 1];
        if (i < nb) boff[i] = run + woff + x - v;
        int tot = wpre[3];
        __syncthreads();
        run += tot;
    }
    if (tid == 0) *rowptrN = run;
    if (tid <= G) {
        int isL = flags[1];
        int lo = 0, hi = N;
        while (lo < hi) {
            int mid = (lo + hi) >> 1;
            int bv = isL ? (int)((const long long*)batch)[mid] : ((const int*)batch)[mid];
            if (bv < tid) lo = mid + 1; else hi = mid;
        }
        bounds[tid] = lo;
    }
}

// phase 3
__global__ void k_scan3(int* __restrict__ rowptr, const int* __restrict__ boff,
                        int* __restrict__ cursor, int N) {
    int i = blockIdx.x * 256 + threadIdx.x;
    if (i < N) {
        int r = rowptr[i] + boff[i >> 8];
        rowptr[i] = r;
        cursor[i] = r;
    }
}

// CSR fill (reads edge_index directly)
__global__ void k_fill(const void* ei, int E, int N, const int* __restrict__ flags,
                       int* __restrict__ cursor, int* __restrict__ col) {
    int e = blockIdx.x * blockDim.x + threadIdx.x;
    if (e >= E) return;
    int s, d;
    if (flags[1]) {
        const long long* p = (const long long*)ei;
        s = (int)p[e];
        d = (int)p[E + e];
    } else {
        const int* p = (const int*)ei;
        s = p[e];
        d = p[E + e];
    }
    if ((unsigned)d < (unsigned)N) {
        int p = atomicAdd(&cursor[d], 1);
        if ((unsigned)p < (unsigned)E) col[p] = ((unsigned)s < (unsigned)N) ? s : 0;
    }
}

// ---------------- mean aggregation: AGG[i] = mean_{j in N(i)} X[j]  (bf16, 128-wide) ----------------
__global__ __launch_bounds__(256) void k_agg(
    const ushort_t* __restrict__ X, const int* __restrict__ rowptr,
    const int* __restrict__ col, ushort_t* __restrict__ AGG, int N) {
    int i = blockIdx.x * 4 + (threadIdx.x >> 6);
    if (i >= N) return;
    int l = threadIdx.x & 63;
    int qn = l >> 4;   // neighbor slot 0..3
    int fo = l & 15;   // feature octet
    const uint4* X8 = (const uint4*)X;  // row = 16 uint4 groups
    int s = rowptr[i], e = rowptr[i + 1];
    float al[4] = {0.f, 0.f, 0.f, 0.f};
    float ah[4] = {0.f, 0.f, 0.f, 0.f};
    int p = s + qn;
    for (; p + 8 < e; p += 12) {  // 12 neighbors per wave-iter, 3 loads/lane in flight
        int j0 = col[p], j1 = col[p + 4], j2 = col[p + 8];
        uint4 u0 = X8[(size_t)j0 * 16 + fo];
        uint4 u1 = X8[(size_t)j1 * 16 + fo];
        uint4 u2 = X8[(size_t)j2 * 16 + fo];
        unsigned w0[4] = {u0.x, u0.y, u0.z, u0.w};
        unsigned w1[4] = {u1.x, u1.y, u1.z, u1.w};
        unsigned w2[4] = {u2.x, u2.y, u2.z, u2.w};
        #pragma unroll
        for (int k = 0; k < 4; ++k) {
            al[k] += __uint_as_float(w0[k] << 16) + __uint_as_float(w1[k] << 16)
                   + __uint_as_float(w2[k] << 16);
            ah[k] += __uint_as_float(w0[k] & 0xFFFF0000u) + __uint_as_float(w1[k] & 0xFFFF0000u)
                   + __uint_as_float(w2[k] & 0xFFFF0000u);
        }
    }
    if (p + 4 < e) {  // 2-deep tail (8 neighbors)
        int j0 = col[p], j1 = col[p + 4];
        uint4 u0 = X8[(size_t)j0 * 16 + fo];
        uint4 u1 = X8[(size_t)j1 * 16 + fo];
        unsigned w0[4] = {u0.x, u0.y, u0.z, u0.w};
        unsigned w1[4] = {u1.x, u1.y, u1.z, u1.w};
        #pragma unroll
        for (int k = 0; k < 4; ++k) {
            al[k] += __uint_as_float(w0[k] << 16) + __uint_as_float(w1[k] << 16);
            ah[k] += __uint_as_float(w0[k] & 0xFFFF0000u) + __uint_as_float(w1[k] & 0xFFFF0000u);
        }
        p += 8;
    }
    if (p < e) {  // final single
        int j = col[p];
        uint4 u = X8[(size_t)j * 16 + fo];
        unsigned w0[4] = {u.x, u.y, u.z, u.w};
        #pragma unroll
        for (int k = 0; k < 4; ++k) {
            al[k] += __uint_as_float(w0[k] << 16);
            ah[k] += __uint_as_float(w0[k] & 0xFFFF0000u);
        }
    }
    #pragma unroll
    for (int k = 0; k < 4; ++k) {
        al[k] += __shfl_xor(al[k], 16, 64);
        al[k] += __shfl_xor(al[k], 32, 64);
        ah[k] += __shfl_xor(ah[k], 16, 64);
        ah[k] += __shfl_xor(ah[k], 32, 64);
    }
    if (qn == 0) {
        int d = e - s;
        float inv = 1.f / (float)(d > 0 ? d : 1);
        uint4 o;
        o.x = f2b2(al[0] * inv, ah[0] * inv);
        o.y = f2b2(al[1] * inv, ah[1] * inv);
        o.z = f2b2(al[2] * inv, ah[2] * inv);
        o.w = f2b2(al[3] * inv, ah[3] * inv);
        ((uint4*)AGG)[(size_t)i * 16 + fo] = o;
    }
}

// ---------------- fused MFMA GEMM + bias + LayerNorm + ReLU (layers 0,1) ----------------
template <int FO>
__global__ __launch_bounds__(256, 2) void k_gemm_ln(
    const ushort_t* __restrict__ AGG, const ushort_t* __restrict__ X,
    const ushort_t* __restrict__ Wb,  // [FO][256] bf16
    const void* bl, const void* gam, const void* bet,
    const int* __restrict__ flags,
    ushort_t* __restrict__ H, int M) {
    constexpr int NT = FO / 16;
    constexpr int R = 2;
    int lane = threadIdx.x & 63;
    int wid = threadIdx.x >> 6;
    int wrow0 = (blockIdx.x * 4 + wid) * (R * 16);
    if (wrow0 >= M) return;
    int isF = flags[0];
    int m = lane & 15;
    int q = lane >> 4;

    int arow[R];
    #pragma unroll
    for (int r = 0; r < R; ++r) {
        int ar = wrow0 + r * 16 + m;
        arow[r] = (ar < M) ? ar : (M - 1);
    }

    f32x4 acc[R][NT];
    #pragma unroll
    for (int r = 0; r < R; ++r)
        #pragma unroll
        for (int nt = 0; nt < NT; ++nt) acc[r][nt] = (f32x4){0.f, 0.f, 0.f, 0.f};

    #pragma unroll
    for (int kk = 0; kk < 8; ++kk) {
        const ushort_t* base = (kk < 4) ? AGG : X;
        int ko = (kk & 3) * 32 + q * 8;
        s16x8 a[R];
        #pragma unroll
        for (int r = 0; r < R; ++r)
            a[r] = *(const s16x8*)(base + (size_t)arow[r] * 128 + ko);
        #pragma unroll
        for (int nt = 0; nt < NT; ++nt) {
            s16x8 b = *(const s16x8*)(Wb + (size_t)(nt * 16 + m) * 256 + kk * 32 + q * 8);
            #pragma unroll
            for (int r = 0; r < R; ++r)
                acc[r][nt] = __builtin_amdgcn_mfma_f32_16x16x32_bf16(a[r], b, acc[r][nt], 0, 0, 0);
        }
    }

    #pragma unroll
    for (int r = 0; r < R; ++r) {
        #pragma unroll
        for (int nt = 0; nt < NT; ++nt) {
            float bv = ldf(bl, nt * 16 + m, isF);
            #pragma unroll
            for (int rr = 0; rr < 4; ++rr) acc[r][nt][rr] += bv;
        }
        float mu[4], rs[4];
        #pragma unroll
        for (int rr = 0; rr < 4; ++rr) {
            float s1 = 0.f, s2 = 0.f;
            #pragma unroll
            for (int nt = 0; nt < NT; ++nt) {
                float v = acc[r][nt][rr];
                s1 += v;
                s2 += v * v;
            }
            #pragma unroll
            for (int off = 1; off < 16; off <<= 1) {
                s1 += __shfl_xor(s1, off, 64);
                s2 += __shfl_xor(s2, off, 64);
            }
            float mm = s1 / (float)FO;
            float var = s2 / (float)FO - mm * mm;
            var = var > 0.f ? var : 0.f;
            mu[rr] = mm;
            rs[rr] = rsqrtf(var + LN_EPS);
        }
        #pragma unroll
        for (int nt = 0; nt < NT; ++nt) {
            int n0 = nt * 16 + m;
            float g = ldf(gam, n0, isF);
            float be = ldf(bet, n0, isF);
            #pragma unroll
            for (int rr = 0; rr < 4; ++rr) {
                int row = wrow0 + r * 16 + q * 4 + rr;
                if (row < M) {
                    float y = (acc[r][nt][rr] - mu[rr]) * rs[rr] * g + be;
                    y = y > 0.f ? y : 0.f;
                    H[(size_t)row * FO + n0] = f2b(y);
                }
            }
        }
    }
}

// ---------------- layer-3 GEMM (no epilogue): T3 = H2 @ [Wl2;Wr2]^T ----------------
__global__ __launch_bounds__(256, 2) void k_gemm3(
    const ushort_t* __restrict__ X,   // H2 [M,128]
    const ushort_t* __restrict__ Wb,  // [128][128] bf16 (stacked Wl2,Wr2)
    ushort_t* __restrict__ T,         // [M,128] bf16
    int M) {
    constexpr int NT = 8;
    constexpr int R = 2;
    int lane = threadIdx.x & 63;
    int wid = threadIdx.x >> 6;
    int wrow0 = (blockIdx.x * 4 + wid) * (R * 16);
    if (wrow0 >= M) return;
    int m = lane & 15;
    int q = lane >> 4;

    int arow[R];
    #pragma unroll
    for (int r = 0; r < R; ++r) {
        int ar = wrow0 + r * 16 + m;
        arow[r] = (ar < M) ? ar : (M - 1);
    }

    f32x4 acc[R][NT];
    #pragma unroll
    for (int r = 0; r < R; ++r)
        #pragma unroll
        for (int nt = 0; nt < NT; ++nt) acc[r][nt] = (f32x4){0.f, 0.f, 0.f, 0.f};

    #pragma unroll
    for (int kk = 0; kk < 4; ++kk) {
        int ko = kk * 32 + q * 8;
        s16x8 a[R];
        #pragma unroll
        for (int r = 0; r < R; ++r)
            a[r] = *(const s16x8*)(X + (size_t)arow[r] * 128 + ko);
        #pragma unroll
        for (int nt = 0; nt < NT; ++nt) {
            s16x8 b = *(const s16x8*)(Wb + (size_t)(nt * 16 + m) * 128 + ko);
            #pragma unroll
            for (int r = 0; r < R; ++r)
                acc[r][nt] = __builtin_amdgcn_mfma_f32_16x16x32_bf16(a[r], b, acc[r][nt], 0, 0, 0);
        }
    }

    #pragma unroll
    for (int r = 0; r < R; ++r)
        #pragma unroll
        for (int nt = 0; nt < NT; ++nt) {
            int n0 = nt * 16 + m;
            #pragma unroll
            for (int rr = 0; rr < 4; ++rr) {
                int row = wrow0 + r * 16 + q * 4 + rr;
                if (row < M) T[(size_t)row * 128 + n0] = f2b(acc[r][nt][rr]);
            }
        }
}

// ---------------- layer-3 aggregate + self + bias + LN + ReLU + POOL (fused) ----------------
// one wave per node; after epilogue, block-level LDS staging then atomics into Z.
__global__ __launch_bounds__(256) void k_agg3(
    const ushort_t* __restrict__ T,  // [N,128]: Y3 | S3
    const int* __restrict__ rowptr, const int* __restrict__ col,
    const void* bl, const void* gam, const void* bet, const int* __restrict__ flags,
    const int* __restrict__ bounds, float* __restrict__ Z, int N, int G) {
    __shared__ float psum[4][64];
    __shared__ float pmax[4][64];
    __shared__ int pg[4];
    int wid = threadIdx.x >> 6;
    int i = blockIdx.x * 4 + wid;
    int valid = (i < N);
    int l = threadIdx.x & 63;
    int qn = l >> 4;
    int fo = l & 15;
    int isF = flags[0];
    const uint2* T2 = (const uint2*)T;  // row = 32 uint2 (Y3 = first 16, S3 = next 16)

    if (valid) {
        int s = rowptr[i], e = rowptr[i + 1];
        float al[2] = {0.f, 0.f};
        float ah[2] = {0.f, 0.f};
        int p = s + qn;
        for (; p + 8 < e; p += 12) {  // 3 gathers in flight
            int j0 = col[p], j1 = col[p + 4], j2 = col[p + 8];
            uint2 u0 = T2[(size_t)j0 * 32 + fo];
            uint2 u1 = T2[(size_t)j1 * 32 + fo];
            uint2 u2 = T2[(size_t)j2 * 32 + fo];
            unsigned w0[2] = {u0.x, u0.y};
            unsigned w1[2] = {u1.x, u1.y};
            unsigned w2[2] = {u2.x, u2.y};
            #pragma unroll
            for (int k = 0; k < 2; ++k) {
                al[k] += __uint_as_float(w0[k] << 16) + __uint_as_float(w1[k] << 16)
                       + __uint_as_float(w2[k] << 16);
                ah[k] += __uint_as_float(w0[k] & 0xFFFF0000u) + __uint_as_float(w1[k] & 0xFFFF0000u)
                       + __uint_as_float(w2[k] & 0xFFFF0000u);
            }
        }
        if (p + 4 < e) {
            int j0 = col[p], j1 = col[p + 4];
            uint2 u0 = T2[(size_t)j0 * 32 + fo];
            uint2 u1 = T2[(size_t)j1 * 32 + fo];
            unsigned w0[2] = {u0.x, u0.y};
            unsigned w1[2] = {u1.x, u1.y};
            #pragma unroll
            for (int k = 0; k < 2; ++k) {
                al[k] += __uint_as_float(w0[k] << 16) + __uint_as_float(w1[k] << 16);
                ah[k] += __uint_as_float(w0[k] & 0xFFFF0000u) + __uint_as_float(w1[k] & 0xFFFF0000u);
            }
            p += 8;
        }
        if (p < e) {
            int j = col[p];
            uint2 u = T2[(size_t)j * 32 + fo];
            unsigned w0[2] = {u.x, u.y};
            #pragma unroll
            for (int k = 0; k < 2; ++k) {
                al[k] += __uint_as_float(w0[k] << 16);
                ah[k] += __uint_as_float(w0[k] & 0xFFFF0000u);
            }
        }
        #pragma unroll
        for (int k = 0; k < 2; ++k) {
            al[k] += __shfl_xor(al[k], 16, 64);
            al[k] += __shfl_xor(al[k], 32, 64);
            ah[k] += __shfl_xor(ah[k], 16, 64);
            ah[k] += __shfl_xor(ah[k], 32, 64);
        }
        int d = e - s;
        float inv = 1.f / (float)(d > 0 ? d : 1);
        uint2 su = T2[(size_t)i * 32 + 16 + fo];  // S3 self
        float v0 = al[0] * inv + __uint_as_float(su.x << 16) + ldf(bl, 4 * fo + 0, isF);
        float v1 = ah[0] * inv + __uint_as_float(su.x & 0xFFFF0000u) + ldf(bl, 4 * fo + 1, isF);
        float v2 = al[1] * inv + __uint_as_float(su.y << 16) + ldf(bl, 4 * fo + 2, isF);
        float v3 = ah[1] * inv + __uint_as_float(su.y & 0xFFFF0000u) + ldf(bl, 4 * fo + 3, isF);
        float s1 = v0 + v1 + v2 + v3;
        float s2 = v0 * v0 + v1 * v1 + v2 * v2 + v3 * v3;
        #pragma unroll
        for (int off = 1; off < 16; off <<= 1) {
            s1 += __shfl_xor(s1, off, 64);
            s2 += __shfl_xor(s2, off, 64);
        }
        float mu = s1 / 64.f;
        float var = s2 / 64.f - mu * mu;
        var = var > 0.f ? var : 0.f;
        float rs = rsqrtf(var + LN_EPS);
        if (qn == 0) {
            float y0 = (v0 - mu) * rs * ldf(gam, 4 * fo + 0, isF) + ldf(bet, 4 * fo + 0, isF);
            float y1 = (v1 - mu) * rs * ldf(gam, 4 * fo + 1, isF) + ldf(bet, 4 * fo + 1, isF);
            float y2 = (v2 - mu) * rs * ldf(gam, 4 * fo + 2, isF) + ldf(bet, 4 * fo + 2, isF);
            float y3 = (v3 - mu) * rs * ldf(gam, 4 * fo + 3, isF) + ldf(bet, 4 * fo + 3, isF);
            y0 = y0 > 0.f ? y0 : 0.f;
            y1 = y1 > 0.f ? y1 : 0.f;
            y2 = y2 > 0.f ? y2 : 0.f;
            y3 = y3 > 0.f ? y3 : 0.f;
            psum[wid][4 * fo + 0] = y0; pmax[wid][4 * fo + 0] = y0;
            psum[wid][4 * fo + 1] = y1; pmax[wid][4 * fo + 1] = y1;
            psum[wid][4 * fo + 2] = y2; pmax[wid][4 * fo + 2] = y2;
            psum[wid][4 * fo + 3] = y3; pmax[wid][4 * fo + 3] = y3;
        }
        if (l == 0) {
            // wave-uniform graph id for node i (bounds[g] <= i < bounds[g+1])
            int lo = 0, hi = G - 1;
            while (lo < hi) {
                int mid = (lo + hi + 1) >> 1;
                if (bounds[mid] <= i) lo = mid; else hi = mid - 1;
            }
            pg[wid] = lo;
        }
    } else if (l == 0) {
        pg[wid] = -1;
    }
    __syncthreads();
    // threads 0..63 (wave 0): combine the 4 node results, flush per graph-run
    int tid = threadIdx.x;
    if (tid < 64) {
        float asum = 0.f, amax = 0.f;
        int gcur = -1;
        #pragma unroll
        for (int w = 0; w < 4; ++w) {
            int g = pg[w];
            if (g < 0) continue;
            if (g != gcur) {
                if (gcur >= 0) {
                    atomicAdd(&Z[gcur * 128 + tid], asum);
                    atomicMax((int*)&Z[gcur * 128 + 64 + tid], __float_as_int(amax));
                }
                gcur = g;
                asum = psum[w][tid];
                amax = pmax[w][tid];
            } else {
                asum += psum[w][tid];
                float m = pmax[w][tid];
                amax = amax > m ? amax : m;
            }
        }
        if (gcur >= 0) {
            atomicAdd(&Z[gcur * 128 + tid], asum);
            atomicMax((int*)&Z[gcur * 128 + 64 + tid], __float_as_int(amax));
        }
    }
}

// ---------------- final MLP; coalesced cW1T; output dtype follows flags[0] ----------------
__global__ void k_mlp(const float* __restrict__ Z, const int* __restrict__ bounds,
                      const float* __restrict__ cW1T, const void* cb1,
                      const void* cW2, const void* cb2,
                      const int* __restrict__ flags, void* __restrict__ out) {
    int g = blockIdx.x;
    int f = threadIdx.x;  // 0..127
    int isF = flags[0];
    __shared__ float z[128];
    __shared__ float hid[128];
    __shared__ float r0[2], r1[2];
    int cnt = bounds[g + 1] - bounds[g];
    float c = (float)(cnt > 0 ? cnt : 1);
    float zv = Z[g * 128 + f];
    if (f < 64) zv /= c;
    z[f] = zv;
    __syncthreads();
    float acc = ldf(cb1, f, isF);
    #pragma unroll 8
    for (int k = 0; k < 128; ++k) acc += z[k] * cW1T[k * 128 + f];  // coalesced
    acc = acc > 0.f ? acc : 0.f;
    hid[f] = acc;
    __syncthreads();
    float p0 = hid[f] * ldf(cW2, f, isF);
    float p1 = hid[f] * ldf(cW2, 128 + f, isF);
    #pragma unroll
    for (int off = 32; off > 0; off >>= 1) {
        p0 += __shfl_xor(p0, off, 64);
        p1 += __shfl_xor(p1, off, 64);
    }
    int w = f >> 6;
    if ((f & 63) == 0) { r0[w] = p0; r1[w] = p1; }
    __syncthreads();
    if (f == 0) {
        float v0 = r0[0] + r0[1] + ldf(cb2, 0, isF);
        float v1 = r1[0] + r1[1] + ldf(cb2, 1, isF);
        if (isF) {
            ((float*)out)[g * 2 + 0] = v0;
            ((float*)out)[g * 2 + 1] = v1;
        } else {
            ((ushort_t*)out)[g * 2 + 0] = f2b(v0);
            ((ushort_t*)out)[g * 2 + 1] = f2b(v1);
        }
    }
}

// ---------------- launch ----------------
extern "C" void kernel_launch(void* const* d_in, const int* in_sizes, int n_in,
                              void* d_out, int out_size, void* d_ws, size_t ws_size,
                              hipStream_t stream) {
    const void* x = d_in[0];
    const void* ei = d_in[1];
    const void* batch = d_in[2];
    const void* Wl0 = d_in[3];
    const void* bl0 = d_in[4];
    const void* Wr0 = d_in[5];
    const void* g0 = d_in[6];
    const void* be0 = d_in[7];
    const void* Wl1 = d_in[8];
    const void* bl1 = d_in[9];
    const void* Wr1 = d_in[10];
    const void* g1 = d_in[11];
    const void* be1 = d_in[12];
    const void* Wl2 = d_in[13];
    const void* bl2 = d_in[14];
    const void* Wr2 = d_in[15];
    const void* g2 = d_in[16];
    const void* be2 = d_in[17];
    const void* cW1 = d_in[18];
    const void* cb1 = d_in[19];
    const void* cW2 = d_in[20];
    const void* cb2 = d_in[21];

    const int N = in_sizes[0] / 128;  // 50000
    const int E = in_sizes[1] / 2;    // 600000
    const int G = 64;

    // workspace carve-up (256B aligned slots)
    char* w = (char*)d_ws;
    size_t o = 0;
    auto take = [&](size_t bytes) -> void* {
        void* p = w + o;
        o = (o + bytes + 255) & ~(size_t)255;
        return p;
    };
    int nb1 = (N + 255) / 256;  // scan phase-1 blocks
    int* flags  = (int*)take(4 * 4);
    int* rowptr = (int*)take((size_t)(N + 1) * 4);
    int* cursor = (int*)take((size_t)N * 4);
    int* deg    = (int*)take((size_t)N * 4);
    int* bsum   = (int*)take((size_t)nb1 * 4);
    int* boff   = (int*)take((size_t)nb1 * 4);
    int* col    = (int*)take((size_t)E * 4);
    int* bounds = (int*)take((size_t)(G + 1) * 4);
    float* Z    = (float*)take((size_t)G * 128 * 4);
    float* cW1T = (float*)take((size_t)128 * 128 * 4);
    ushort_t* Wb0 = (ushort_t*)take((size_t)128 * 256 * 2);
    ushort_t* Wb1 = (ushort_t*)take((size_t)128 * 256 * 2);
    ushort_t* Wb2 = (ushort_t*)take((size_t)128 * 128 * 2);
    ushort_t* AGG = (ushort_t*)take((size_t)N * 128 * 2);
    ushort_t* H1  = (ushort_t*)take((size_t)N * 128 * 2);
    ushort_t* H2  = (ushort_t*)take((size_t)N * 128 * 2);
    ushort_t* XB  = H2;   // x-as-bf16 overlays H2 (dead before H2 written)
    ushort_t* T3  = AGG;  // layer-3 GEMM out overlays AGG (dead after layer-2 gemm)
    if (o > ws_size) return;

    int eb = (E + 255) / 256;
    int xb = (N * 128 / 4 + 255) / 256;
    int wb = (2 * 32768 + 2 * 16384 + 255) / 256;
    k_detect_zero<<<nb1, 256, 0, stream>>>(Wl0, ei, flags, deg, Z, N);
    k_prep<<<xb + eb + wb, 256, 0, stream>>>(x, XB, N * 128 / 4, xb,
                                             ei, E, N, deg, eb,
                                             Wl0, Wr0, Wl1, Wr1, Wl2, Wr2, cW1,
                                             Wb0, Wb1, Wb2, cW1T, flags);
    k_scan1<<<nb1, 256, 0, stream>>>(deg, N, rowptr, bsum);
    k_scan2<<<1, 256, 0, stream>>>(bsum, nb1, boff, rowptr + N, batch, N, G, flags, bounds);
    k_scan3<<<nb1, 256, 0, stream>>>(rowptr, boff, cursor, N);
    k_fill<<<eb, 256, 0, stream>>>(ei, E, N, flags, cursor, col);

    int gb = (N + 127) / 128;  // gemm blocks (4 waves x 32 rows)
    int ab = (N + 3) / 4;      // agg blocks (4 waves = 4 nodes each)

    // layer 0: XB -> H1
    k_agg<<<ab, 256, 0, stream>>>(XB, rowptr, col, AGG, N);
    k_gemm_ln<128><<<gb, 256, 0, stream>>>(AGG, XB, Wb0, bl0, g0, be0, flags, H1, N);
    // layer 1: H1 -> H2 (overwrites XB; XB dead)
    k_agg<<<ab, 256, 0, stream>>>(H1, rowptr, col, AGG, N);
    k_gemm_ln<128><<<gb, 256, 0, stream>>>(AGG, H1, Wb1, bl1, g1, be1, flags, H2, N);
    // layer 2 (reordered): T3 = H2 @ [Wl2;Wr2]^T, then aggregate + epilogue + POOL (fused)
    k_gemm3<<<gb, 256, 0, stream>>>(H2, Wb2, T3, N);
    k_agg3<<<ab, 256, 0, stream>>>(T3, rowptr, col, bl2, g2, be2, flags, bounds, Z, N, G);

    k_mlp<<<G, 128, 0, stream>>>(Z, bounds, cW1T, cb1, cW2, cb2, flags, d_out);
}

// Round 16
// 353.077 us; speedup vs baseline: 1.0682x; 1.0310x over previous
//
#include <hip/hip_runtime.h>

typedef unsigned short ushort_t;
typedef short s16x8 __attribute__((ext_vector_type(8)));
typedef float f32x4 __attribute__((ext_vector_type(4)));

#define LN_EPS 1e-5f

// ---- bf16 <-> f32 helpers ----
__device__ __forceinline__ float b2f(ushort_t u) {
    return __uint_as_float(((unsigned)u) << 16);
}
__device__ __forceinline__ ushort_t f2b(float f) {
    unsigned b = __float_as_uint(f);
    b += 0x7FFFu + ((b >> 16) & 1u);  // round-to-nearest-even
    return (ushort_t)(b >> 16);
}
__device__ __forceinline__ unsigned f2b2(float lo, float hi) {  // pack two bf16
    return (unsigned)f2b(lo) | ((unsigned)f2b(hi) << 16);
}
// dtype-flexible load: isF ? fp32 : bf16
__device__ __forceinline__ float ldf(const void* p, size_t i, int isF) {
    return isF ? ((const float*)p)[i] : b2f(((const ushort_t*)p)[i]);
}

// harness-compat symbol (unused)
__global__ void GraphSAGE_36026185678961_kernel() {}

// ---------------- dtype detect (block 0) + zero-init deg, Z ----------------
__global__ void k_detect_zero(const void* w0, const void* ei, int* __restrict__ flags,
                              int* __restrict__ deg, float* __restrict__ Z, int N) {
    int i = blockIdx.x * blockDim.x + threadIdx.x;
    if (i < N) deg[i] = 0;
    if (i < 64 * 128) Z[i] = 0.f;
    if (blockIdx.x == 0 && threadIdx.x < 64) {
        int t = threadIdx.x;
        const ushort_t* u = (const ushort_t*)w0;
        int pass = 0;
        #pragma unroll
        for (int k = 0; k < 4; ++k) {
            ushort_t v = u[t * 4 + k];
            int ex = (v >> 7) & 0xFF;
            if (ex == 0 || (ex >= 0x60 && ex <= 0x7E)) pass++;
        }
        const unsigned* w = (const unsigned*)ei;
        int nz = (w[2 * t + 1] != 0u) ? 1 : 0;
        #pragma unroll
        for (int off = 32; off; off >>= 1) {
            pass += __shfl_down(pass, off, 64);
            nz += __shfl_down(nz, off, 64);
        }
        if (t == 0) {
            flags[0] = (pass < 205) ? 1 : 0;
            flags[1] = (nz == 0) ? 1 : 0;
        }
    }
}

// ---------------- fused prep: xconv | hist | weight repack | cW1T | fp32 params ----------------
__global__ void k_prep(const void* X, ushort_t* __restrict__ XB, int total4, int xb,
                       const void* ei, int E, int N, int* __restrict__ deg, int eb,
                       const void* Wl0, const void* Wr0, const void* Wl1, const void* Wr1,
                       const void* Wl2, const void* Wr2, const void* cW1,
                       const void* bl0, const void* g0, const void* be0,
                       const void* bl1, const void* g1, const void* be1,
                       const void* bl2, const void* g2, const void* be2,
                       const void* cb1, const void* cW2, const void* cb2,
                       ushort_t* __restrict__ Wb0, ushort_t* __restrict__ Wb1,
                       ushort_t* __restrict__ Wb2, float* __restrict__ cW1T,
                       float* __restrict__ P0, float* __restrict__ P1,
                       float* __restrict__ P2, float* __restrict__ PM,
                       const int* __restrict__ flags) {
    int b = blockIdx.x;
    if (b < xb) {
        int idx = b * 256 + threadIdx.x;
        if (idx >= total4) return;
        if (flags[0]) {
            float4 v = ((const float4*)X)[idx];
            ushort4 o;
            o.x = f2b(v.x); o.y = f2b(v.y); o.z = f2b(v.z); o.w = f2b(v.w);
            ((ushort4*)XB)[idx] = o;
        } else {
            ((ushort4*)XB)[idx] = ((const ushort4*)X)[idx];
        }
    } else if (b < xb + eb) {
        int e = (b - xb) * 256 + threadIdx.x;
        if (e >= E) return;
        int d = flags[1] ? (int)((const long long*)ei)[E + e] : ((const int*)ei)[E + e];
        if ((unsigned)d < (unsigned)N) atomicAdd(&deg[d], 1);
    } else {
        int t = (b - xb - eb) * 256 + threadIdx.x;
        int isF = flags[0];
        if (t < 2 * 32768) {  // layers 0,1: Wb [f][256]
            const void* Wl = (t < 32768) ? Wl0 : Wl1;
            const void* Wr = (t < 32768) ? Wr0 : Wr1;
            ushort_t* Wb = (t < 32768) ? Wb0 : Wb1;
            int base = t & 32767;
            int f = base >> 8, k = base & 255;
            if (isF) {
                float v = (k < 128) ? ((const float*)Wl)[f * 128 + k]
                                    : ((const float*)Wr)[f * 128 + (k - 128)];
                Wb[base] = f2b(v);
            } else {
                Wb[base] = ((const ushort_t*)((k < 128) ? Wl : Wr))[f * 128 + (k & 127)];
            }
        } else {
            int t0 = t - 2 * 32768;
            if (t0 < 16384) {  // layer 2: Wb2 [128][128], rows 0..63 Wl2, 64..127 Wr2
                int f = t0 >> 7, k = t0 & 127;
                const void* W = (f < 64) ? Wl2 : Wr2;
                int fr = f & 63;
                Wb2[t0] = isF ? f2b(((const float*)W)[fr * 128 + k])
                              : ((const ushort_t*)W)[fr * 128 + k];
            } else if (t0 < 32768) {  // cW1 transpose -> fp32 [k][f]
                int base = t0 - 16384;
                int k = base >> 7, f = base & 127;
                cW1T[base] = ldf(cW1, f * 128 + k, isF);
            } else {
                int j = t0 - 32768;
                if (j < 384) {  // P0 = bl0|g0|be0
                    P0[j] = (j < 128) ? ldf(bl0, j, isF)
                          : (j < 256) ? ldf(g0, j - 128, isF) : ldf(be0, j - 256, isF);
                } else if (j < 768) {  // P1
                    int jj = j - 384;
                    P1[jj] = (jj < 128) ? ldf(bl1, jj, isF)
                           : (jj < 256) ? ldf(g1, jj - 128, isF) : ldf(be1, jj - 256, isF);
                } else if (j < 960) {  // P2 = bl2|g2|be2 (64 each)
                    int jj = j - 768;
                    P2[jj] = (jj < 64) ? ldf(bl2, jj, isF)
                           : (jj < 128) ? ldf(g2, jj - 64, isF) : ldf(be2, jj - 128, isF);
                } else if (j < 1346) {  // PM = cb1(128)|cW2(256)|cb2(2)
                    int jj = j - 960;
                    PM[jj] = (jj < 128) ? ldf(cb1, jj, isF)
                           : (jj < 384) ? ldf(cW2, jj - 128, isF) : ldf(cb2, jj - 384, isF);
                }
            }
        }
    }
}

// hierarchical scan, phase 1
__global__ void k_scan1(const int* __restrict__ deg, int N,
                        int* __restrict__ rowptr, int* __restrict__ bsum) {
    __shared__ int wsum[4];
    __shared__ int wpre[4];
    int tid = threadIdx.x;
    int lane = tid & 63;
    int w = tid >> 6;
    int i = blockIdx.x * 256 + tid;
    int v = (i < N) ? deg[i] : 0;
    int x = v;
    #pragma unroll
    for (int off = 1; off < 64; off <<= 1) {
        int t = __shfl_up(x, off, 64);
        if (lane >= off) x += t;
    }
    if (lane == 63) wsum[w] = x;
    __syncthreads();
    if (tid == 0) {
        int a = wsum[0]; wpre[0] = a;
        a += wsum[1]; wpre[1] = a;
        a += wsum[2]; wpre[2] = a;
        a += wsum[3]; wpre[3] = a;
    }
    __syncthreads();
    int woff = (w == 0) ? 0 : wpre[w - 1];
    if (i < N) rowptr[i] = woff + x - v;
    if (tid == 0) bsum[blockIdx.x] = wpre[3];
}

// phase 2: scan of block sums + graph bounds (fused)
__global__ void k_scan2(const int* __restrict__ bsum, int nb,
                        int* __restrict__ boff, int* __restrict__ rowptrN,
                        const void* batch, int N, int G, const int* __restrict__ flags,
                        int* __restrict__ bounds) {
    __shared__ int wsum[4];
    __shared__ int wpre[4];
    int tid = threadIdx.x;
    int lane = tid & 63;
    int w = tid >> 6;
    int run = 0;
    for (int base = 0; base < nb; base += 256) {
        int i = base + tid;
        int v = (i < nb) ? bsum[i] : 0;
        int x = v;
        #pragma unroll
        for (int off = 1; off < 64; off <<= 1) {
            int t = __shfl_up(x, off, 64);
            if (lane >= off) x += t;
        }
        if (lane == 63) wsum[w] = x;
        __syncthreads();
        if (tid == 0) {
            int a = wsum[0]; wpre[0] = a;
            a += wsum[1]; wpre[1] = a;
            a += wsum[2]; wpre[2] = a;
            a += wsum[3]; wpre[3] = a;
        }
        __syncthreads();
        int woff = (w == 0) ? 0 : wpre[w - 1];
        if (i < nb) boff[i] = run + woff + x - v;
        int tot = wpre[3];
        __syncthreads();
        run += tot;
    }
    if (tid == 0) *rowptrN = run;
    if (tid <= G) {
        int isL = flags[1];
        int lo = 0, hi = N;
        while (lo < hi) {
            int mid = (lo + hi) >> 1;
            int bv = isL ? (int)((const long long*)batch)[mid] : ((const int*)batch)[mid];
            if (bv < tid) lo = mid + 1; else hi = mid;
        }
        bounds[tid] = lo;
    }
}

// phase 3
__global__ void k_scan3(int* __restrict__ rowptr, const int* __restrict__ boff,
                        int* __restrict__ cursor, int N) {
    int i = blockIdx.x * 256 + threadIdx.x;
    if (i < N) {
        int r = rowptr[i] + boff[i >> 8];
        rowptr[i] = r;
        cursor[i] = r;
    }
}

// CSR fill (reads edge_index directly)
__global__ void k_fill(const void* ei, int E, int N, const int* __restrict__ flags,
                       int* __restrict__ cursor, int* __restrict__ col) {
    int e = blockIdx.x * blockDim.x + threadIdx.x;
    if (e >= E) return;
    int s, d;
    if (flags[1]) {
        const long long* p = (const long long*)ei;
        s = (int)p[e];
        d = (int)p[E + e];
    } else {
        const int* p = (const int*)ei;
        s = p[e];
        d = p[E + e];
    }
    if ((unsigned)d < (unsigned)N) {
        int p = atomicAdd(&cursor[d], 1);
        if ((unsigned)p < (unsigned)E) col[p] = ((unsigned)s < (unsigned)N) ? s : 0;
    }
}

// ---------------- mean aggregation: AGG[i] = mean_{j in N(i)} X[j]  (bf16, 128-wide) ----------------
__global__ __launch_bounds__(256) void k_agg(
    const ushort_t* __restrict__ X, const int* __restrict__ rowptr,
    const int* __restrict__ col, ushort_t* __restrict__ AGG, int N) {
    int i = blockIdx.x * 4 + (threadIdx.x >> 6);
    if (i >= N) return;
    int l = threadIdx.x & 63;
    int qn = l >> 4;   // neighbor slot 0..3
    int fo = l & 15;   // feature octet
    const uint4* X8 = (const uint4*)X;  // row = 16 uint4 groups
    int s = rowptr[i], e = rowptr[i + 1];
    float al[4] = {0.f, 0.f, 0.f, 0.f};
    float ah[4] = {0.f, 0.f, 0.f, 0.f};
    int p = s + qn;
    for (; p + 8 < e; p += 12) {  // 12 neighbors per wave-iter, 3 loads in flight
        int j0 = col[p], j1 = col[p + 4], j2 = col[p + 8];
        uint4 u0 = X8[(size_t)j0 * 16 + fo];
        uint4 u1 = X8[(size_t)j1 * 16 + fo];
        uint4 u2 = X8[(size_t)j2 * 16 + fo];
        unsigned w0[4] = {u0.x, u0.y, u0.z, u0.w};
        unsigned w1[4] = {u1.x, u1.y, u1.z, u1.w};
        unsigned w2[4] = {u2.x, u2.y, u2.z, u2.w};
        #pragma unroll
        for (int k = 0; k < 4; ++k) {
            al[k] += __uint_as_float(w0[k] << 16) + __uint_as_float(w1[k] << 16)
                   + __uint_as_float(w2[k] << 16);
            ah[k] += __uint_as_float(w0[k] & 0xFFFF0000u) + __uint_as_float(w1[k] & 0xFFFF0000u)
                   + __uint_as_float(w2[k] & 0xFFFF0000u);
        }
    }
    if (p + 4 < e) {  // 2-deep tail
        int j0 = col[p], j1 = col[p + 4];
        uint4 u0 = X8[(size_t)j0 * 16 + fo];
        uint4 u1 = X8[(size_t)j1 * 16 + fo];
        unsigned w0[4] = {u0.x, u0.y, u0.z, u0.w};
        unsigned w1[4] = {u1.x, u1.y, u1.z, u1.w};
        #pragma unroll
        for (int k = 0; k < 4; ++k) {
            al[k] += __uint_as_float(w0[k] << 16) + __uint_as_float(w1[k] << 16);
            ah[k] += __uint_as_float(w0[k] & 0xFFFF0000u) + __uint_as_float(w1[k] & 0xFFFF0000u);
        }
        p += 8;
    }
    if (p < e) {  // final single
        int j = col[p];
        uint4 u = X8[(size_t)j * 16 + fo];
        unsigned w0[4] = {u.x, u.y, u.z, u.w};
        #pragma unroll
        for (int k = 0; k < 4; ++k) {
            al[k] += __uint_as_float(w0[k] << 16);
            ah[k] += __uint_as_float(w0[k] & 0xFFFF0000u);
        }
    }
    #pragma unroll
    for (int k = 0; k < 4; ++k) {
        al[k] += __shfl_xor(al[k], 16, 64);
        al[k] += __shfl_xor(al[k], 32, 64);
        ah[k] += __shfl_xor(ah[k], 16, 64);
        ah[k] += __shfl_xor(ah[k], 32, 64);
    }
    if (qn == 0) {
        int d = e - s;
        float inv = 1.f / (float)(d > 0 ? d : 1);
        uint4 o;
        o.x = f2b2(al[0] * inv, ah[0] * inv);
        o.y = f2b2(al[1] * inv, ah[1] * inv);
        o.z = f2b2(al[2] * inv, ah[2] * inv);
        o.w = f2b2(al[3] * inv, ah[3] * inv);
        ((uint4*)AGG)[(size_t)i * 16 + fo] = o;
    }
}

// ---------------- fused MFMA GEMM + bias + LayerNorm + ReLU (layers 0,1) ----------------
// P = fp32[3*FO]: bias | gamma | beta
template <int FO>
__global__ __launch_bounds__(256, 2) void k_gemm_ln(
    const ushort_t* __restrict__ AGG, const ushort_t* __restrict__ X,
    const ushort_t* __restrict__ Wb,  // [FO][256] bf16
    const float* __restrict__ P,
    ushort_t* __restrict__ H, int M) {
    constexpr int NT = FO / 16;
    constexpr int R = 2;
    int lane = threadIdx.x & 63;
    int wid = threadIdx.x >> 6;
    int wrow0 = (blockIdx.x * 4 + wid) * (R * 16);
    if (wrow0 >= M) return;
    int m = lane & 15;
    int q = lane >> 4;

    int arow[R];
    #pragma unroll
    for (int r = 0; r < R; ++r) {
        int ar = wrow0 + r * 16 + m;
        arow[r] = (ar < M) ? ar : (M - 1);
    }

    f32x4 acc[R][NT];
    #pragma unroll
    for (int r = 0; r < R; ++r)
        #pragma unroll
        for (int nt = 0; nt < NT; ++nt) acc[r][nt] = (f32x4){0.f, 0.f, 0.f, 0.f};

    #pragma unroll
    for (int kk = 0; kk < 8; ++kk) {
        const ushort_t* base = (kk < 4) ? AGG : X;
        int ko = (kk & 3) * 32 + q * 8;
        s16x8 a[R];
        #pragma unroll
        for (int r = 0; r < R; ++r)
            a[r] = *(const s16x8*)(base + (size_t)arow[r] * 128 + ko);
        #pragma unroll
        for (int nt = 0; nt < NT; ++nt) {
            s16x8 b = *(const s16x8*)(Wb + (size_t)(nt * 16 + m) * 256 + kk * 32 + q * 8);
            #pragma unroll
            for (int r = 0; r < R; ++r)
                acc[r][nt] = __builtin_amdgcn_mfma_f32_16x16x32_bf16(a[r], b, acc[r][nt], 0, 0, 0);
        }
    }

    #pragma unroll
    for (int r = 0; r < R; ++r) {
        #pragma unroll
        for (int nt = 0; nt < NT; ++nt) {
            float bv = P[nt * 16 + m];
            #pragma unroll
            for (int rr = 0; rr < 4; ++rr) acc[r][nt][rr] += bv;
        }
        float mu[4], rs[4];
        #pragma unroll
        for (int rr = 0; rr < 4; ++rr) {
            float s1 = 0.f, s2 = 0.f;
            #pragma unroll
            for (int nt = 0; nt < NT; ++nt) {
                float v = acc[r][nt][rr];
                s1 += v;
                s2 += v * v;
            }
            #pragma unroll
            for (int off = 1; off < 16; off <<= 1) {
                s1 += __shfl_xor(s1, off, 64);
                s2 += __shfl_xor(s2, off, 64);
            }
            float mm = s1 / (float)FO;
            float var = s2 / (float)FO - mm * mm;
            var = var > 0.f ? var : 0.f;
            mu[rr] = mm;
            rs[rr] = rsqrtf(var + LN_EPS);
        }
        #pragma unroll
        for (int nt = 0; nt < NT; ++nt) {
            int n0 = nt * 16 + m;
            float g = P[FO + n0];
            float be = P[2 * FO + n0];
            #pragma unroll
            for (int rr = 0; rr < 4; ++rr) {
                int row = wrow0 + r * 16 + q * 4 + rr;
                if (row < M) {
                    float y = (acc[r][nt][rr] - mu[rr]) * rs[rr] * g + be;
                    y = y > 0.f ? y : 0.f;
                    H[(size_t)row * FO + n0] = f2b(y);
                }
            }
        }
    }
}

// ---------------- layer-3 GEMM (no epilogue): T3 = H2 @ [Wl2;Wr2]^T ----------------
__global__ __launch_bounds__(256, 2) void k_gemm3(
    const ushort_t* __restrict__ X,   // H2 [M,128]
    const ushort_t* __restrict__ Wb,  // [128][128] bf16 (stacked Wl2,Wr2)
    ushort_t* __restrict__ T,         // [M,128] bf16
    int M) {
    constexpr int NT = 8;
    constexpr int R = 2;
    int lane = threadIdx.x & 63;
    int wid = threadIdx.x >> 6;
    int wrow0 = (blockIdx.x * 4 + wid) * (R * 16);
    if (wrow0 >= M) return;
    int m = lane & 15;
    int q = lane >> 4;

    int arow[R];
    #pragma unroll
    for (int r = 0; r < R; ++r) {
        int ar = wrow0 + r * 16 + m;
        arow[r] = (ar < M) ? ar : (M - 1);
    }

    f32x4 acc[R][NT];
    #pragma unroll
    for (int r = 0; r < R; ++r)
        #pragma unroll
        for (int nt = 0; nt < NT; ++nt) acc[r][nt] = (f32x4){0.f, 0.f, 0.f, 0.f};

    #pragma unroll
    for (int kk = 0; kk < 4; ++kk) {
        int ko = kk * 32 + q * 8;
        s16x8 a[R];
        #pragma unroll
        for (int r = 0; r < R; ++r)
            a[r] = *(const s16x8*)(X + (size_t)arow[r] * 128 + ko);
        #pragma unroll
        for (int nt = 0; nt < NT; ++nt) {
            s16x8 b = *(const s16x8*)(Wb + (size_t)(nt * 16 + m) * 128 + ko);
            #pragma unroll
            for (int r = 0; r < R; ++r)
                acc[r][nt] = __builtin_amdgcn_mfma_f32_16x16x32_bf16(a[r], b, acc[r][nt], 0, 0, 0);
        }
    }

    #pragma unroll
    for (int r = 0; r < R; ++r)
        #pragma unroll
        for (int nt = 0; nt < NT; ++nt) {
            int n0 = nt * 16 + m;
            #pragma unroll
            for (int rr = 0; rr < 4; ++rr) {
                int row = wrow0 + r * 16 + q * 4 + rr;
                if (row < M) T[(size_t)row * 128 + n0] = f2b(acc[r][nt][rr]);
            }
        }
}

// ---------------- layer-3 aggregate + self + bias + LN + ReLU (P2 fp32 params) ----------------
__global__ __launch_bounds__(256) void k_agg3(
    const ushort_t* __restrict__ T,  // [N,128]: Y3 | S3
    const int* __restrict__ rowptr, const int* __restrict__ col,
    const float* __restrict__ P2,    // [192]: bl2|g2|be2
    ushort_t* __restrict__ H, int N) {  // H: [N,64]
    int i = blockIdx.x * 4 + (threadIdx.x >> 6);
    if (i >= N) return;
    int l = threadIdx.x & 63;
    int qn = l >> 4;
    int fo = l & 15;
    const uint2* T2 = (const uint2*)T;  // row = 32 uint2 (Y3 first 16, S3 next 16)
    int s = rowptr[i], e = rowptr[i + 1];
    float al[2] = {0.f, 0.f};
    float ah[2] = {0.f, 0.f};
    int p = s + qn;
    for (; p + 8 < e; p += 12) {  // 3 gathers in flight
        int j0 = col[p], j1 = col[p + 4], j2 = col[p + 8];
        uint2 u0 = T2[(size_t)j0 * 32 + fo];
        uint2 u1 = T2[(size_t)j1 * 32 + fo];
        uint2 u2 = T2[(size_t)j2 * 32 + fo];
        unsigned w0[2] = {u0.x, u0.y};
        unsigned w1[2] = {u1.x, u1.y};
        unsigned w2[2] = {u2.x, u2.y};
        #pragma unroll
        for (int k = 0; k < 2; ++k) {
            al[k] += __uint_as_float(w0[k] << 16) + __uint_as_float(w1[k] << 16)
                   + __uint_as_float(w2[k] << 16);
            ah[k] += __uint_as_float(w0[k] & 0xFFFF0000u) + __uint_as_float(w1[k] & 0xFFFF0000u)
                   + __uint_as_float(w2[k] & 0xFFFF0000u);
        }
    }
    if (p + 4 < e) {
        int j0 = col[p], j1 = col[p + 4];
        uint2 u0 = T2[(size_t)j0 * 32 + fo];
        uint2 u1 = T2[(size_t)j1 * 32 + fo];
        unsigned w0[2] = {u0.x, u0.y};
        unsigned w1[2] = {u1.x, u1.y};
        #pragma unroll
        for (int k = 0; k < 2; ++k) {
            al[k] += __uint_as_float(w0[k] << 16) + __uint_as_float(w1[k] << 16);
            ah[k] += __uint_as_float(w0[k] & 0xFFFF0000u) + __uint_as_float(w1[k] & 0xFFFF0000u);
        }
        p += 8;
    }
    if (p < e) {
        int j = col[p];
        uint2 u = T2[(size_t)j * 32 + fo];
        unsigned w0[2] = {u.x, u.y};
        #pragma unroll
        for (int k = 0; k < 2; ++k) {
            al[k] += __uint_as_float(w0[k] << 16);
            ah[k] += __uint_as_float(w0[k] & 0xFFFF0000u);
        }
    }
    #pragma unroll
    for (int k = 0; k < 2; ++k) {
        al[k] += __shfl_xor(al[k], 16, 64);
        al[k] += __shfl_xor(al[k], 32, 64);
        ah[k] += __shfl_xor(ah[k], 16, 64);
        ah[k] += __shfl_xor(ah[k], 32, 64);
    }
    int d = e - s;
    float inv = 1.f / (float)(d > 0 ? d : 1);
    uint2 su = T2[(size_t)i * 32 + 16 + fo];  // S3 self
    float4 bl4 = *(const float4*)&P2[4 * fo];
    float v0 = al[0] * inv + __uint_as_float(su.x << 16) + bl4.x;
    float v1 = ah[0] * inv + __uint_as_float(su.x & 0xFFFF0000u) + bl4.y;
    float v2 = al[1] * inv + __uint_as_float(su.y << 16) + bl4.z;
    float v3 = ah[1] * inv + __uint_as_float(su.y & 0xFFFF0000u) + bl4.w;
    float s1 = v0 + v1 + v2 + v3;
    float s2 = v0 * v0 + v1 * v1 + v2 * v2 + v3 * v3;
    #pragma unroll
    for (int off = 1; off < 16; off <<= 1) {
        s1 += __shfl_xor(s1, off, 64);
        s2 += __shfl_xor(s2, off, 64);
    }
    float mu = s1 / 64.f;
    float var = s2 / 64.f - mu * mu;
    var = var > 0.f ? var : 0.f;
    float rs = rsqrtf(var + LN_EPS);
    if (qn == 0) {
        float4 g4 = *(const float4*)&P2[64 + 4 * fo];
        float4 b4 = *(const float4*)&P2[128 + 4 * fo];
        float y0 = (v0 - mu) * rs * g4.x + b4.x;
        float y1 = (v1 - mu) * rs * g4.y + b4.y;
        float y2 = (v2 - mu) * rs * g4.z + b4.z;
        float y3 = (v3 - mu) * rs * g4.w + b4.w;
        y0 = y0 > 0.f ? y0 : 0.f;
        y1 = y1 > 0.f ? y1 : 0.f;
        y2 = y2 > 0.f ? y2 : 0.f;
        y3 = y3 > 0.f ? y3 : 0.f;
        uint2 o;
        o.x = f2b2(y0, y1);
        o.y = f2b2(y2, y3);
        ((uint2*)H)[(size_t)i * 16 + fo] = o;
    }
}

// ---------------- pooling: Z[64][128]: cols 0..63 sum, 64..127 max ----------------
__global__ __launch_bounds__(256) void k_pool(
    const ushort_t* __restrict__ H,  // [N,64], post-ReLU (>=0)
    const int* __restrict__ bounds, float* __restrict__ Z, int N) {
    int g = blockIdx.x >> 4;
    int chunk = blockIdx.x & 15;
    int lane = threadIdx.x & 31;   // feature pair
    int sub = threadIdx.x >> 5;    // 0..7
    int strm = chunk * 8 + sub;    // 0..127
    int s = bounds[g], e = bounds[g + 1];
    s = s < 0 ? 0 : (s > N ? N : s);
    e = e < s ? s : (e > N ? N : e);
    const unsigned* H2 = (const unsigned*)H;
    float sl = 0.f, sh = 0.f, ml = 0.f, mh = 0.f;
    for (int i = s + strm; i < e; i += 128) {
        unsigned u = H2[(size_t)i * 32 + lane];
        float vl = __uint_as_float(u << 16);
        float vh = __uint_as_float(u & 0xFFFF0000u);
        sl += vl; sh += vh;
        ml = ml > vl ? ml : vl;
        mh = mh > vh ? mh : vh;
    }
    int f0 = lane * 2;
    atomicAdd(&Z[g * 128 + f0], sl);
    atomicAdd(&Z[g * 128 + f0 + 1], sh);
    atomicMax((int*)&Z[g * 128 + 64 + f0], __float_as_int(ml));
    atomicMax((int*)&Z[g * 128 + 64 + f0 + 1], __float_as_int(mh));
}

// ---------------- final MLP; coalesced cW1T + PM fp32 params ----------------
__global__ void k_mlp(const float* __restrict__ Z, const int* __restrict__ bounds,
                      const float* __restrict__ cW1T, const float* __restrict__ PM,
                      const int* __restrict__ flags, void* __restrict__ out) {
    int g = blockIdx.x;
    int f = threadIdx.x;  // 0..127
    __shared__ float z[128];
    __shared__ float hid[128];
    __shared__ float r0[2], r1[2];
    int cnt = bounds[g + 1] - bounds[g];
    float c = (float)(cnt > 0 ? cnt : 1);
    float zv = Z[g * 128 + f];
    if (f < 64) zv /= c;
    z[f] = zv;
    __syncthreads();
    float acc = PM[f];  // cb1
    #pragma unroll 8
    for (int k = 0; k < 128; ++k) acc += z[k] * cW1T[k * 128 + f];  // coalesced
    acc = acc > 0.f ? acc : 0.f;
    hid[f] = acc;
    __syncthreads();
    float p0 = hid[f] * PM[128 + f];        // cW2 row 0
    float p1 = hid[f] * PM[256 + f];        // cW2 row 1
    #pragma unroll
    for (int off = 32; off > 0; off >>= 1) {
        p0 += __shfl_xor(p0, off, 64);
        p1 += __shfl_xor(p1, off, 64);
    }
    int w = f >> 6;
    if ((f & 63) == 0) { r0[w] = p0; r1[w] = p1; }
    __syncthreads();
    if (f == 0) {
        float v0 = r0[0] + r0[1] + PM[384];
        float v1 = r1[0] + r1[1] + PM[385];
        if (flags[0]) {
            ((float*)out)[g * 2 + 0] = v0;
            ((float*)out)[g * 2 + 1] = v1;
        } else {
            ((ushort_t*)out)[g * 2 + 0] = f2b(v0);
            ((ushort_t*)out)[g * 2 + 1] = f2b(v1);
        }
    }
}

// ---------------- launch ----------------
extern "C" void kernel_launch(void* const* d_in, const int* in_sizes, int n_in,
                              void* d_out, int out_size, void* d_ws, size_t ws_size,
                              hipStream_t stream) {
    const void* x = d_in[0];
    const void* ei = d_in[1];
    const void* batch = d_in[2];
    const void* Wl0 = d_in[3];
    const void* bl0 = d_in[4];
    const void* Wr0 = d_in[5];
    const void* g0 = d_in[6];
    const void* be0 = d_in[7];
    const void* Wl1 = d_in[8];
    const void* bl1 = d_in[9];
    const void* Wr1 = d_in[10];
    const void* g1 = d_in[11];
    const void* be1 = d_in[12];
    const void* Wl2 = d_in[13];
    const void* bl2 = d_in[14];
    const void* Wr2 = d_in[15];
    const void* g2 = d_in[16];
    const void* be2 = d_in[17];
    const void* cW1 = d_in[18];
    const void* cb1 = d_in[19];
    const void* cW2 = d_in[20];
    const void* cb2 = d_in[21];

    const int N = in_sizes[0] / 128;  // 50000
    const int E = in_sizes[1] / 2;    // 600000
    const int G = 64;

    // workspace carve-up (256B aligned slots)
    char* w = (char*)d_ws;
    size_t o = 0;
    auto take = [&](size_t bytes) -> void* {
        void* p = w + o;
        o = (o + bytes + 255) & ~(size_t)255;
        return p;
    };
    int nb1 = (N + 255) / 256;  // scan phase-1 blocks
    int* flags  = (int*)take(4 * 4);
    int* rowptr = (int*)take((size_t)(N + 1) * 4);
    int* cursor = (int*)take((size_t)N * 4);
    int* deg    = (int*)take((size_t)N * 4);
    int* bsum   = (int*)take((size_t)nb1 * 4);
    int* boff   = (int*)take((size_t)nb1 * 4);
    int* col    = (int*)take((size_t)E * 4);
    int* bounds = (int*)take((size_t)(G + 1) * 4);
    float* Z    = (float*)take((size_t)G * 128 * 4);
    float* cW1T = (float*)take((size_t)128 * 128 * 4);
    float* P0   = (float*)take(384 * 4);
    float* P1   = (float*)take(384 * 4);
    float* P2   = (float*)take(192 * 4);
    float* PM   = (float*)take(386 * 4);
    ushort_t* Wb0 = (ushort_t*)take((size_t)128 * 256 * 2);
    ushort_t* Wb1 = (ushort_t*)take((size_t)128 * 256 * 2);
    ushort_t* Wb2 = (ushort_t*)take((size_t)128 * 128 * 2);
    ushort_t* AGG = (ushort_t*)take((size_t)N * 128 * 2);
    ushort_t* H1  = (ushort_t*)take((size_t)N * 128 * 2);
    ushort_t* H2  = (ushort_t*)take((size_t)N * 128 * 2);
    ushort_t* XB  = H2;   // x-as-bf16 overlays H2 (dead before H2 written)
    ushort_t* T3  = AGG;  // layer-3 GEMM out overlays AGG (dead after layer-2 gemm)
    ushort_t* H3  = H1;   // [N,64] reuses H1
    if (o > ws_size) return;

    int eb = (E + 255) / 256;
    int xb = (N * 128 / 4 + 255) / 256;
    int wtot = 2 * 32768 + 16384 + 16384 + 1346;
    int wb = (wtot + 255) / 256;
    k_detect_zero<<<nb1, 256, 0, stream>>>(Wl0, ei, flags, deg, Z, N);
    k_prep<<<xb + eb + wb, 256, 0, stream>>>(x, XB, N * 128 / 4, xb,
                                             ei, E, N, deg, eb,
                                             Wl0, Wr0, Wl1, Wr1, Wl2, Wr2, cW1,
                                             bl0, g0, be0, bl1, g1, be1, bl2, g2, be2,
                                             cb1, cW2, cb2,
                                             Wb0, Wb1, Wb2, cW1T, P0, P1, P2, PM, flags);
    k_scan1<<<nb1, 256, 0, stream>>>(deg, N, rowptr, bsum);
    k_scan2<<<1, 256, 0, stream>>>(bsum, nb1, boff, rowptr + N, batch, N, G, flags, bounds);
    k_scan3<<<nb1, 256, 0, stream>>>(rowptr, boff, cursor, N);
    k_fill<<<eb, 256, 0, stream>>>(ei, E, N, flags, cursor, col);

    int gb = (N + 127) / 128;  // gemm blocks (4 waves x 32 rows)
    int ab = (N + 3) / 4;      // agg blocks (4 waves = 4 nodes each)

    // layer 0: XB -> H1
    k_agg<<<ab, 256, 0, stream>>>(XB, rowptr, col, AGG, N);
    k_gemm_ln<128><<<gb, 256, 0, stream>>>(AGG, XB, Wb0, P0, H1, N);
    // layer 1: H1 -> H2 (overwrites XB; XB dead)
    k_agg<<<ab, 256, 0, stream>>>(H1, rowptr, col, AGG, N);
    k_gemm_ln<128><<<gb, 256, 0, stream>>>(AGG, H1, Wb1, P1, H2, N);
    // layer 2 (reordered): T3 = H2 @ [Wl2;Wr2]^T, then aggregate + epilogue
    k_gemm3<<<gb, 256, 0, stream>>>(H2, Wb2, T3, N);
    k_agg3<<<ab, 256, 0, stream>>>(T3, rowptr, col, P2, H3, N);

    k_pool<<<G * 16, 256, 0, stream>>>(H3, bounds, Z, N);
    k_mlp<<<G, 128, 0, stream>>>(Z, bounds, cW1T, PM, flags, d_out);
}

// Round 17
// 331.190 us; speedup vs baseline: 1.1388x; 1.0661x over previous
//
#include <hip/hip_runtime.h>

typedef unsigned short ushort_t;
typedef short s16x8 __attribute__((ext_vector_type(8)));
typedef float f32x4 __attribute__((ext_vector_type(4)));

#define LN_EPS 1e-5f

// ---- bf16 <-> f32 helpers ----
__device__ __forceinline__ float b2f(ushort_t u) {
    return __uint_as_float(((unsigned)u) << 16);
}
__device__ __forceinline__ ushort_t f2b(float f) {
    unsigned b = __float_as_uint(f);
    b += 0x7FFFu + ((b >> 16) & 1u);  // round-to-nearest-even
    return (ushort_t)(b >> 16);
}
__device__ __forceinline__ unsigned f2b2(float lo, float hi) {  // pack two bf16
    return (unsigned)f2b(lo) | ((unsigned)f2b(hi) << 16);
}
// dtype-flexible load: isF ? fp32 : bf16
__device__ __forceinline__ float ldf(const void* p, size_t i, int isF) {
    return isF ? ((const float*)p)[i] : b2f(((const ushort_t*)p)[i]);
}

// harness-compat symbol (unused)
__global__ void GraphSAGE_36026185678961_kernel() {}

// ---------------- dtype detect (block 0) + zero-init deg, Z ----------------
__global__ void k_detect_zero(const void* w0, const void* ei, int* __restrict__ flags,
                              int* __restrict__ deg, float* __restrict__ Z, int N) {
    int i = blockIdx.x * blockDim.x + threadIdx.x;
    if (i < N) deg[i] = 0;
    if (i < 64 * 128) Z[i] = 0.f;
    if (blockIdx.x == 0 && threadIdx.x < 64) {
        int t = threadIdx.x;
        const ushort_t* u = (const ushort_t*)w0;
        int pass = 0;
        #pragma unroll
        for (int k = 0; k < 4; ++k) {
            ushort_t v = u[t * 4 + k];
            int ex = (v >> 7) & 0xFF;
            if (ex == 0 || (ex >= 0x60 && ex <= 0x7E)) pass++;
        }
        const unsigned* w = (const unsigned*)ei;
        int nz = (w[2 * t + 1] != 0u) ? 1 : 0;
        #pragma unroll
        for (int off = 32; off; off >>= 1) {
            pass += __shfl_down(pass, off, 64);
            nz += __shfl_down(nz, off, 64);
        }
        if (t == 0) {
            flags[0] = (pass < 205) ? 1 : 0;
            flags[1] = (nz == 0) ? 1 : 0;
        }
    }
}

// ---------------- fused prep: xconv | hist | weight repack | cW1T | fp32 params ----------------
__global__ void k_prep(const void* X, ushort_t* __restrict__ XB, int total4, int xb,
                       const void* ei, int E, int N, int* __restrict__ deg, int eb,
                       const void* Wl0, const void* Wr0, const void* Wl1, const void* Wr1,
                       const void* Wl2, const void* Wr2, const void* cW1,
                       const void* bl0, const void* g0, const void* be0,
                       const void* bl1, const void* g1, const void* be1,
                       const void* bl2, const void* g2, const void* be2,
                       const void* cb1, const void* cW2, const void* cb2,
                       ushort_t* __restrict__ Wb0, ushort_t* __restrict__ Wb1,
                       ushort_t* __restrict__ Wb2, float* __restrict__ cW1T,
                       float* __restrict__ P0, float* __restrict__ P1,
                       float* __restrict__ P2, float* __restrict__ PM,
                       const int* __restrict__ flags) {
    int b = blockIdx.x;
    if (b < xb) {
        int idx = b * 256 + threadIdx.x;
        if (idx >= total4) return;
        if (flags[0]) {
            float4 v = ((const float4*)X)[idx];
            ushort4 o;
            o.x = f2b(v.x); o.y = f2b(v.y); o.z = f2b(v.z); o.w = f2b(v.w);
            ((ushort4*)XB)[idx] = o;
        } else {
            ((ushort4*)XB)[idx] = ((const ushort4*)X)[idx];
        }
    } else if (b < xb + eb) {
        int e = (b - xb) * 256 + threadIdx.x;
        if (e >= E) return;
        int d = flags[1] ? (int)((const long long*)ei)[E + e] : ((const int*)ei)[E + e];
        if ((unsigned)d < (unsigned)N) atomicAdd(&deg[d], 1);
    } else {
        int t = (b - xb - eb) * 256 + threadIdx.x;
        int isF = flags[0];
        if (t < 2 * 32768) {  // layers 0,1: Wb [f][256]
            const void* Wl = (t < 32768) ? Wl0 : Wl1;
            const void* Wr = (t < 32768) ? Wr0 : Wr1;
            ushort_t* Wb = (t < 32768) ? Wb0 : Wb1;
            int base = t & 32767;
            int f = base >> 8, k = base & 255;
            if (isF) {
                float v = (k < 128) ? ((const float*)Wl)[f * 128 + k]
                                    : ((const float*)Wr)[f * 128 + (k - 128)];
                Wb[base] = f2b(v);
            } else {
                Wb[base] = ((const ushort_t*)((k < 128) ? Wl : Wr))[f * 128 + (k & 127)];
            }
        } else {
            int t0 = t - 2 * 32768;
            if (t0 < 16384) {  // layer 2: Wb2 [128][128], rows 0..63 Wl2, 64..127 Wr2
                int f = t0 >> 7, k = t0 & 127;
                const void* W = (f < 64) ? Wl2 : Wr2;
                int fr = f & 63;
                Wb2[t0] = isF ? f2b(((const float*)W)[fr * 128 + k])
                              : ((const ushort_t*)W)[fr * 128 + k];
            } else if (t0 < 32768) {  // cW1 transpose -> fp32 [k][f]
                int base = t0 - 16384;
                int k = base >> 7, f = base & 127;
                cW1T[base] = ldf(cW1, f * 128 + k, isF);
            } else {
                int j = t0 - 32768;
                if (j < 384) {  // P0 = bl0|g0|be0
                    P0[j] = (j < 128) ? ldf(bl0, j, isF)
                          : (j < 256) ? ldf(g0, j - 128, isF) : ldf(be0, j - 256, isF);
                } else if (j < 768) {  // P1
                    int jj = j - 384;
                    P1[jj] = (jj < 128) ? ldf(bl1, jj, isF)
                           : (jj < 256) ? ldf(g1, jj - 128, isF) : ldf(be1, jj - 256, isF);
                } else if (j < 960) {  // P2 = bl2|g2|be2 (64 each)
                    int jj = j - 768;
                    P2[jj] = (jj < 64) ? ldf(bl2, jj, isF)
                           : (jj < 128) ? ldf(g2, jj - 64, isF) : ldf(be2, jj - 128, isF);
                } else if (j < 1346) {  // PM = cb1(128)|cW2(256)|cb2(2)
                    int jj = j - 960;
                    PM[jj] = (jj < 128) ? ldf(cb1, jj, isF)
                           : (jj < 384) ? ldf(cW2, jj - 128, isF) : ldf(cb2, jj - 384, isF);
                }
            }
        }
    }
}

// hierarchical scan, phase 1
__global__ void k_scan1(const int* __restrict__ deg, int N,
                        int* __restrict__ rowptr, int* __restrict__ bsum) {
    __shared__ int wsum[4];
    __shared__ int wpre[4];
    int tid = threadIdx.x;
    int lane = tid & 63;
    int w = tid >> 6;
    int i = blockIdx.x * 256 + tid;
    int v = (i < N) ? deg[i] : 0;
    int x = v;
    #pragma unroll
    for (int off = 1; off < 64; off <<= 1) {
        int t = __shfl_up(x, off, 64);
        if (lane >= off) x += t;
    }
    if (lane == 63) wsum[w] = x;
    __syncthreads();
    if (tid == 0) {
        int a = wsum[0]; wpre[0] = a;
        a += wsum[1]; wpre[1] = a;
        a += wsum[2]; wpre[2] = a;
        a += wsum[3]; wpre[3] = a;
    }
    __syncthreads();
    int woff = (w == 0) ? 0 : wpre[w - 1];
    if (i < N) rowptr[i] = woff + x - v;
    if (tid == 0) bsum[blockIdx.x] = wpre[3];
}

// phase 2: scan of block sums + graph bounds (fused)
__global__ void k_scan2(const int* __restrict__ bsum, int nb,
                        int* __restrict__ boff, int* __restrict__ rowptrN,
                        const void* batch, int N, int G, const int* __restrict__ flags,
                        int* __restrict__ bounds) {
    __shared__ int wsum[4];
    __shared__ int wpre[4];
    int tid = threadIdx.x;
    int lane = tid & 63;
    int w = tid >> 6;
    int run = 0;
    for (int base = 0; base < nb; base += 256) {
        int i = base + tid;
        int v = (i < nb) ? bsum[i] : 0;
        int x = v;
        #pragma unroll
        for (int off = 1; off < 64; off <<= 1) {
            int t = __shfl_up(x, off, 64);
            if (lane >= off) x += t;
        }
        if (lane == 63) wsum[w] = x;
        __syncthreads();
        if (tid == 0) {
            int a = wsum[0]; wpre[0] = a;
            a += wsum[1]; wpre[1] = a;
            a += wsum[2]; wpre[2] = a;
            a += wsum[3]; wpre[3] = a;
        }
        __syncthreads();
        int woff = (w == 0) ? 0 : wpre[w - 1];
        if (i < nb) boff[i] = run + woff + x - v;
        int tot = wpre[3];
        __syncthreads();
        run += tot;
    }
    if (tid == 0) *rowptrN = run;
    if (tid <= G) {
        int isL = flags[1];
        int lo = 0, hi = N;
        while (lo < hi) {
            int mid = (lo + hi) >> 1;
            int bv = isL ? (int)((const long long*)batch)[mid] : ((const int*)batch)[mid];
            if (bv < tid) lo = mid + 1; else hi = mid;
        }
        bounds[tid] = lo;
    }
}

// phase 3
__global__ void k_scan3(int* __restrict__ rowptr, const int* __restrict__ boff,
                        int* __restrict__ cursor, int N) {
    int i = blockIdx.x * 256 + threadIdx.x;
    if (i < N) {
        int r = rowptr[i] + boff[i >> 8];
        rowptr[i] = r;
        cursor[i] = r;
    }
}

// CSR fill (reads edge_index directly)
__global__ void k_fill(const void* ei, int E, int N, const int* __restrict__ flags,
                       int* __restrict__ cursor, int* __restrict__ col) {
    int e = blockIdx.x * blockDim.x + threadIdx.x;
    if (e >= E) return;
    int s, d;
    if (flags[1]) {
        const long long* p = (const long long*)ei;
        s = (int)p[e];
        d = (int)p[E + e];
    } else {
        const int* p = (const int*)ei;
        s = p[e];
        d = p[E + e];
    }
    if ((unsigned)d < (unsigned)N) {
        int p = atomicAdd(&cursor[d], 1);
        if ((unsigned)p < (unsigned)E) col[p] = ((unsigned)s < (unsigned)N) ? s : 0;
    }
}

// ---------------- mean aggregation: AGG[i] = mean_{j in N(i)} X[j]  (bf16, 128-wide) ----------------
__global__ __launch_bounds__(256) void k_agg(
    const ushort_t* __restrict__ X, const int* __restrict__ rowptr,
    const int* __restrict__ col, ushort_t* __restrict__ AGG, int N) {
    int i = blockIdx.x * 4 + (threadIdx.x >> 6);
    if (i >= N) return;
    int l = threadIdx.x & 63;
    int qn = l >> 4;   // neighbor slot 0..3
    int fo = l & 15;   // feature octet
    const uint4* X8 = (const uint4*)X;  // row = 16 uint4 groups
    int s = rowptr[i], e = rowptr[i + 1];
    float al[4] = {0.f, 0.f, 0.f, 0.f};
    float ah[4] = {0.f, 0.f, 0.f, 0.f};
    int p = s + qn;
    for (; p + 8 < e; p += 12) {  // 12 neighbors per wave-iter, 3 loads in flight
        int j0 = col[p], j1 = col[p + 4], j2 = col[p + 8];
        uint4 u0 = X8[(size_t)j0 * 16 + fo];
        uint4 u1 = X8[(size_t)j1 * 16 + fo];
        uint4 u2 = X8[(size_t)j2 * 16 + fo];
        unsigned w0[4] = {u0.x, u0.y, u0.z, u0.w};
        unsigned w1[4] = {u1.x, u1.y, u1.z, u1.w};
        unsigned w2[4] = {u2.x, u2.y, u2.z, u2.w};
        #pragma unroll
        for (int k = 0; k < 4; ++k) {
            al[k] += __uint_as_float(w0[k] << 16) + __uint_as_float(w1[k] << 16)
                   + __uint_as_float(w2[k] << 16);
            ah[k] += __uint_as_float(w0[k] & 0xFFFF0000u) + __uint_as_float(w1[k] & 0xFFFF0000u)
                   + __uint_as_float(w2[k] & 0xFFFF0000u);
        }
    }
    if (p + 4 < e) {  // 2-deep tail
        int j0 = col[p], j1 = col[p + 4];
        uint4 u0 = X8[(size_t)j0 * 16 + fo];
        uint4 u1 = X8[(size_t)j1 * 16 + fo];
        unsigned w0[4] = {u0.x, u0.y, u0.z, u0.w};
        unsigned w1[4] = {u1.x, u1.y, u1.z, u1.w};
        #pragma unroll
        for (int k = 0; k < 4; ++k) {
            al[k] += __uint_as_float(w0[k] << 16) + __uint_as_float(w1[k] << 16);
            ah[k] += __uint_as_float(w0[k] & 0xFFFF0000u) + __uint_as_float(w1[k] & 0xFFFF0000u);
        }
        p += 8;
    }
    if (p < e) {  // final single
        int j = col[p];
        uint4 u = X8[(size_t)j * 16 + fo];
        unsigned w0[4] = {u.x, u.y, u.z, u.w};
        #pragma unroll
        for (int k = 0; k < 4; ++k) {
            al[k] += __uint_as_float(w0[k] << 16);
            ah[k] += __uint_as_float(w0[k] & 0xFFFF0000u);
        }
    }
    #pragma unroll
    for (int k = 0; k < 4; ++k) {
        al[k] += __shfl_xor(al[k], 16, 64);
        al[k] += __shfl_xor(al[k], 32, 64);
        ah[k] += __shfl_xor(ah[k], 16, 64);
        ah[k] += __shfl_xor(ah[k], 32, 64);
    }
    if (qn == 0) {
        int d = e - s;
        float inv = 1.f / (float)(d > 0 ? d : 1);
        uint4 o;
        o.x = f2b2(al[0] * inv, ah[0] * inv);
        o.y = f2b2(al[1] * inv, ah[1] * inv);
        o.z = f2b2(al[2] * inv, ah[2] * inv);
        o.w = f2b2(al[3] * inv, ah[3] * inv);
        ((uint4*)AGG)[(size_t)i * 16 + fo] = o;
    }
}

// ---------------- fused MFMA GEMM + bias + LayerNorm + ReLU (layers 0,1) ----------------
// B staged in LDS fragment-major (Bs[kk][nt][lane][8]): 32KB per K-half, 2 stages.
// P = fp32[3*FO]: bias | gamma | beta
template <int FO>
__global__ __launch_bounds__(256, 2) void k_gemm_ln(
    const ushort_t* __restrict__ AGG, const ushort_t* __restrict__ X,
    const ushort_t* __restrict__ Wb,  // [FO][256] bf16
    const float* __restrict__ P,
    ushort_t* __restrict__ H, int M) {
    constexpr int NT = FO / 16;  // 8
    constexpr int R = 2;
    __shared__ ushort_t Bs[4][NT][64][8];  // 32 KB for NT=8

    int tid = threadIdx.x;
    int lane = tid & 63;
    int wid = tid >> 6;
    int wrow0 = (blockIdx.x * 4 + wid) * (R * 16);
    int active = (wrow0 < M);
    int m = lane & 15;
    int q = lane >> 4;

    int arow[R];
    #pragma unroll
    for (int r = 0; r < R; ++r) {
        int ar = wrow0 + r * 16 + m;
        arow[r] = (ar < M) ? ar : (M - 1);
        if (!active) arow[r] = 0;
    }

    f32x4 acc[R][NT];
    #pragma unroll
    for (int r = 0; r < R; ++r)
        #pragma unroll
        for (int nt = 0; nt < NT; ++nt) acc[r][nt] = (f32x4){0.f, 0.f, 0.f, 0.f};

    #pragma unroll
    for (int h = 0; h < 2; ++h) {  // K-half: h=0 -> AGG/cols 0..127, h=1 -> X/cols 128..255
        // stage 32 KB of B fragments: 2048 uint4 entries, 8 per thread
        __syncthreads();
        #pragma unroll
        for (int it = 0; it < 8; ++it) {
            int idx = it * 256 + tid;       // [0, 2048)
            int sl = idx & 63;              // lane within fragment
            int snt = (idx >> 6) & (NT - 1);
            int skk = idx >> 9;             // 0..3
            int sm = sl & 15, sq = sl >> 4;
            ((uint4*)Bs)[idx] = *(const uint4*)(Wb + (size_t)(snt * 16 + sm) * 256
                                                + h * 128 + skk * 32 + sq * 8);
        }
        __syncthreads();
        const ushort_t* base = h ? X : AGG;
        #pragma unroll
        for (int kk = 0; kk < 4; ++kk) {
            int ko = kk * 32 + q * 8;
            s16x8 a[R];
            #pragma unroll
            for (int r = 0; r < R; ++r)
                a[r] = *(const s16x8*)(base + (size_t)arow[r] * 128 + ko);
            #pragma unroll
            for (int nt = 0; nt < NT; ++nt) {
                s16x8 b = *(const s16x8*)&Bs[kk][nt][lane][0];
                #pragma unroll
                for (int r = 0; r < R; ++r)
                    acc[r][nt] = __builtin_amdgcn_mfma_f32_16x16x32_bf16(a[r], b, acc[r][nt], 0, 0, 0);
            }
        }
    }
    if (!active) return;

    #pragma unroll
    for (int r = 0; r < R; ++r) {
        #pragma unroll
        for (int nt = 0; nt < NT; ++nt) {
            float bv = P[nt * 16 + m];
            #pragma unroll
            for (int rr = 0; rr < 4; ++rr) acc[r][nt][rr] += bv;
        }
        float mu[4], rs[4];
        #pragma unroll
        for (int rr = 0; rr < 4; ++rr) {
            float s1 = 0.f, s2 = 0.f;
            #pragma unroll
            for (int nt = 0; nt < NT; ++nt) {
                float v = acc[r][nt][rr];
                s1 += v;
                s2 += v * v;
            }
            #pragma unroll
            for (int off = 1; off < 16; off <<= 1) {
                s1 += __shfl_xor(s1, off, 64);
                s2 += __shfl_xor(s2, off, 64);
            }
            float mm = s1 / (float)FO;
            float var = s2 / (float)FO - mm * mm;
            var = var > 0.f ? var : 0.f;
            mu[rr] = mm;
            rs[rr] = rsqrtf(var + LN_EPS);
        }
        #pragma unroll
        for (int nt = 0; nt < NT; ++nt) {
            int n0 = nt * 16 + m;
            float g = P[FO + n0];
            float be = P[2 * FO + n0];
            #pragma unroll
            for (int rr = 0; rr < 4; ++rr) {
                int row = wrow0 + r * 16 + q * 4 + rr;
                if (row < M) {
                    float y = (acc[r][nt][rr] - mu[rr]) * rs[rr] * g + be;
                    y = y > 0.f ? y : 0.f;
                    H[(size_t)row * FO + n0] = f2b(y);
                }
            }
        }
    }
}

// ---------------- layer-3 GEMM (no epilogue): T3 = H2 @ [Wl2;Wr2]^T ----------------
// Full B (32KB) staged once in LDS fragment-major.
__global__ __launch_bounds__(256, 2) void k_gemm3(
    const ushort_t* __restrict__ X,   // H2 [M,128]
    const ushort_t* __restrict__ Wb,  // [128][128] bf16 (stacked Wl2,Wr2)
    ushort_t* __restrict__ T,         // [M,128] bf16
    int M) {
    constexpr int NT = 8;
    constexpr int R = 2;
    __shared__ ushort_t Bs[4][NT][64][8];  // 32 KB

    int tid = threadIdx.x;
    int lane = tid & 63;
    int wid = tid >> 6;
    int wrow0 = (blockIdx.x * 4 + wid) * (R * 16);
    int active = (wrow0 < M);
    int m = lane & 15;
    int q = lane >> 4;

    // stage B: 2048 uint4 entries, 8 per thread
    #pragma unroll
    for (int it = 0; it < 8; ++it) {
        int idx = it * 256 + tid;
        int sl = idx & 63;
        int snt = (idx >> 6) & 7;
        int skk = idx >> 9;
        int sm = sl & 15, sq = sl >> 4;
        ((uint4*)Bs)[idx] = *(const uint4*)(Wb + (size_t)(snt * 16 + sm) * 128
                                            + skk * 32 + sq * 8);
    }
    __syncthreads();
    if (!active) return;

    int arow[R];
    #pragma unroll
    for (int r = 0; r < R; ++r) {
        int ar = wrow0 + r * 16 + m;
        arow[r] = (ar < M) ? ar : (M - 1);
    }

    f32x4 acc[R][NT];
    #pragma unroll
    for (int r = 0; r < R; ++r)
        #pragma unroll
        for (int nt = 0; nt < NT; ++nt) acc[r][nt] = (f32x4){0.f, 0.f, 0.f, 0.f};

    #pragma unroll
    for (int kk = 0; kk < 4; ++kk) {
        int ko = kk * 32 + q * 8;
        s16x8 a[R];
        #pragma unroll
        for (int r = 0; r < R; ++r)
            a[r] = *(const s16x8*)(X + (size_t)arow[r] * 128 + ko);
        #pragma unroll
        for (int nt = 0; nt < NT; ++nt) {
            s16x8 b = *(const s16x8*)&Bs[kk][nt][lane][0];
            #pragma unroll
            for (int r = 0; r < R; ++r)
                acc[r][nt] = __builtin_amdgcn_mfma_f32_16x16x32_bf16(a[r], b, acc[r][nt], 0, 0, 0);
        }
    }

    #pragma unroll
    for (int r = 0; r < R; ++r)
        #pragma unroll
        for (int nt = 0; nt < NT; ++nt) {
            int n0 = nt * 16 + m;
            #pragma unroll
            for (int rr = 0; rr < 4; ++rr) {
                int row = wrow0 + r * 16 + q * 4 + rr;
                if (row < M) T[(size_t)row * 128 + n0] = f2b(acc[r][nt][rr]);
            }
        }
}

// ---------------- layer-3 aggregate + self + bias + LN + ReLU (P2 fp32 params) ----------------
__global__ __launch_bounds__(256) void k_agg3(
    const ushort_t* __restrict__ T,  // [N,128]: Y3 | S3
    const int* __restrict__ rowptr, const int* __restrict__ col,
    const float* __restrict__ P2,    // [192]: bl2|g2|be2
    ushort_t* __restrict__ H, int N) {  // H: [N,64]
    int i = blockIdx.x * 4 + (threadIdx.x >> 6);
    if (i >= N) return;
    int l = threadIdx.x & 63;
    int qn = l >> 4;
    int fo = l & 15;
    const uint2* T2 = (const uint2*)T;  // row = 32 uint2 (Y3 first 16, S3 next 16)
    int s = rowptr[i], e = rowptr[i + 1];
    float al[2] = {0.f, 0.f};
    float ah[2] = {0.f, 0.f};
    int p = s + qn;
    for (; p + 8 < e; p += 12) {  // 3 gathers in flight
        int j0 = col[p], j1 = col[p + 4], j2 = col[p + 8];
        uint2 u0 = T2[(size_t)j0 * 32 + fo];
        uint2 u1 = T2[(size_t)j1 * 32 + fo];
        uint2 u2 = T2[(size_t)j2 * 32 + fo];
        unsigned w0[2] = {u0.x, u0.y};
        unsigned w1[2] = {u1.x, u1.y};
        unsigned w2[2] = {u2.x, u2.y};
        #pragma unroll
        for (int k = 0; k < 2; ++k) {
            al[k] += __uint_as_float(w0[k] << 16) + __uint_as_float(w1[k] << 16)
                   + __uint_as_float(w2[k] << 16);
            ah[k] += __uint_as_float(w0[k] & 0xFFFF0000u) + __uint_as_float(w1[k] & 0xFFFF0000u)
                   + __uint_as_float(w2[k] & 0xFFFF0000u);
        }
    }
    if (p + 4 < e) {
        int j0 = col[p], j1 = col[p + 4];
        uint2 u0 = T2[(size_t)j0 * 32 + fo];
        uint2 u1 = T2[(size_t)j1 * 32 + fo];
        unsigned w0[2] = {u0.x, u0.y};
        unsigned w1[2] = {u1.x, u1.y};
        #pragma unroll
        for (int k = 0; k < 2; ++k) {
            al[k] += __uint_as_float(w0[k] << 16) + __uint_as_float(w1[k] << 16);
            ah[k] += __uint_as_float(w0[k] & 0xFFFF0000u) + __uint_as_float(w1[k] & 0xFFFF0000u);
        }
        p += 8;
    }
    if (p < e) {
        int j = col[p];
        uint2 u = T2[(size_t)j * 32 + fo];
        unsigned w0[2] = {u.x, u.y};
        #pragma unroll
        for (int k = 0; k < 2; ++k) {
            al[k] += __uint_as_float(w0[k] << 16);
            ah[k] += __uint_as_float(w0[k] & 0xFFFF0000u);
        }
    }
    #pragma unroll
    for (int k = 0; k < 2; ++k) {
        al[k] += __shfl_xor(al[k], 16, 64);
        al[k] += __shfl_xor(al[k], 32, 64);
        ah[k] += __shfl_xor(ah[k], 16, 64);
        ah[k] += __shfl_xor(ah[k], 32, 64);
    }
    int d = e - s;
    float inv = 1.f / (float)(d > 0 ? d : 1);
    uint2 su = T2[(size_t)i * 32 + 16 + fo];  // S3 self
    float4 bl4 = *(const float4*)&P2[4 * fo];
    float v0 = al[0] * inv + __uint_as_float(su.x << 16) + bl4.x;
    float v1 = ah[0] * inv + __uint_as_float(su.x & 0xFFFF0000u) + bl4.y;
    float v2 = al[1] * inv + __uint_as_float(su.y << 16) + bl4.z;
    float v3 = ah[1] * inv + __uint_as_float(su.y & 0xFFFF0000u) + bl4.w;
    float s1 = v0 + v1 + v2 + v3;
    float s2 = v0 * v0 + v1 * v1 + v2 * v2 + v3 * v3;
    #pragma unroll
    for (int off = 1; off < 16; off <<= 1) {
        s1 += __shfl_xor(s1, off, 64);
        s2 += __shfl_xor(s2, off, 64);
    }
    float mu = s1 / 64.f;
    float var = s2 / 64.f - mu * mu;
    var = var > 0.f ? var : 0.f;
    float rs = rsqrtf(var + LN_EPS);
    if (qn == 0) {
        float4 g4 = *(const float4*)&P2[64 + 4 * fo];
        float4 b4 = *(const float4*)&P2[128 + 4 * fo];
        float y0 = (v0 - mu) * rs * g4.x + b4.x;
        float y1 = (v1 - mu) * rs * g4.y + b4.y;
        float y2 = (v2 - mu) * rs * g4.z + b4.z;
        float y3 = (v3 - mu) * rs * g4.w + b4.w;
        y0 = y0 > 0.f ? y0 : 0.f;
        y1 = y1 > 0.f ? y1 : 0.f;
        y2 = y2 > 0.f ? y2 : 0.f;
        y3 = y3 > 0.f ? y3 : 0.f;
        uint2 o;
        o.x = f2b2(y0, y1);
        o.y = f2b2(y2, y3);
        ((uint2*)H)[(size_t)i * 16 + fo] = o;
    }
}

// ---------------- pooling: Z[64][128]: cols 0..63 sum, 64..127 max ----------------
__global__ __launch_bounds__(256) void k_pool(
    const ushort_t* __restrict__ H,  // [N,64], post-ReLU (>=0)
    const int* __restrict__ bounds, float* __restrict__ Z, int N) {
    int g = blockIdx.x >> 4;
    int chunk = blockIdx.x & 15;
    int lane = threadIdx.x & 31;   // feature pair
    int sub = threadIdx.x >> 5;    // 0..7
    int strm = chunk * 8 + sub;    // 0..127
    int s = bounds[g], e = bounds[g + 1];
    s = s < 0 ? 0 : (s > N ? N : s);
    e = e < s ? s : (e > N ? N : e);
    const unsigned* H2 = (const unsigned*)H;
    float sl = 0.f, sh = 0.f, ml = 0.f, mh = 0.f;
    for (int i = s + strm; i < e; i += 128) {
        unsigned u = H2[(size_t)i * 32 + lane];
        float vl = __uint_as_float(u << 16);
        float vh = __uint_as_float(u & 0xFFFF0000u);
        sl += vl; sh += vh;
        ml = ml > vl ? ml : vl;
        mh = mh > vh ? mh : vh;
    }
    int f0 = lane * 2;
    atomicAdd(&Z[g * 128 + f0], sl);
    atomicAdd(&Z[g * 128 + f0 + 1], sh);
    atomicMax((int*)&Z[g * 128 + 64 + f0], __float_as_int(ml));
    atomicMax((int*)&Z[g * 128 + 64 + f0 + 1], __float_as_int(mh));
}

// ---------------- final MLP; coalesced cW1T + PM fp32 params ----------------
__global__ void k_mlp(const float* __restrict__ Z, const int* __restrict__ bounds,
                      const float* __restrict__ cW1T, const float* __restrict__ PM,
                      const int* __restrict__ flags, void* __restrict__ out) {
    int g = blockIdx.x;
    int f = threadIdx.x;  // 0..127
    __shared__ float z[128];
    __shared__ float hid[128];
    __shared__ float r0[2], r1[2];
    int cnt = bounds[g + 1] - bounds[g];
    float c = (float)(cnt > 0 ? cnt : 1);
    float zv = Z[g * 128 + f];
    if (f < 64) zv /= c;
    z[f] = zv;
    __syncthreads();
    float acc = PM[f];  // cb1
    #pragma unroll 8
    for (int k = 0; k < 128; ++k) acc += z[k] * cW1T[k * 128 + f];  // coalesced
    acc = acc > 0.f ? acc : 0.f;
    hid[f] = acc;
    __syncthreads();
    float p0 = hid[f] * PM[128 + f];        // cW2 row 0
    float p1 = hid[f] * PM[256 + f];        // cW2 row 1
    #pragma unroll
    for (int off = 32; off > 0; off >>= 1) {
        p0 += __shfl_xor(p0, off, 64);
        p1 += __shfl_xor(p1, off, 64);
    }
    int w = f >> 6;
    if ((f & 63) == 0) { r0[w] = p0; r1[w] = p1; }
    __syncthreads();
    if (f == 0) {
        float v0 = r0[0] + r0[1] + PM[384];
        float v1 = r1[0] + r1[1] + PM[385];
        if (flags[0]) {
            ((float*)out)[g * 2 + 0] = v0;
            ((float*)out)[g * 2 + 1] = v1;
        } else {
            ((ushort_t*)out)[g * 2 + 0] = f2b(v0);
            ((ushort_t*)out)[g * 2 + 1] = f2b(v1);
        }
    }
}

// ---------------- launch ----------------
extern "C" void kernel_launch(void* const* d_in, const int* in_sizes, int n_in,
                              void* d_out, int out_size, void* d_ws, size_t ws_size,
                              hipStream_t stream) {
    const void* x = d_in[0];
    const void* ei = d_in[1];
    const void* batch = d_in[2];
    const void* Wl0 = d_in[3];
    const void* bl0 = d_in[4];
    const void* Wr0 = d_in[5];
    const void* g0 = d_in[6];
    const void* be0 = d_in[7];
    const void* Wl1 = d_in[8];
    const void* bl1 = d_in[9];
    const void* Wr1 = d_in[10];
    const void* g1 = d_in[11];
    const void* be1 = d_in[12];
    const void* Wl2 = d_in[13];
    const void* bl2 = d_in[14];
    const void* Wr2 = d_in[15];
    const void* g2 = d_in[16];
    const void* be2 = d_in[17];
    const void* cW1 = d_in[18];
    const void* cb1 = d_in[19];
    const void* cW2 = d_in[20];
    const void* cb2 = d_in[21];

    const int N = in_sizes[0] / 128;  // 50000
    const int E = in_sizes[1] / 2;    // 600000
    const int G = 64;

    // workspace carve-up (256B aligned slots)
    char* w = (char*)d_ws;
    size_t o = 0;
    auto take = [&](size_t bytes) -> void* {
        void* p = w + o;
        o = (o + bytes + 255) & ~(size_t)255;
        return p;
    };
    int nb1 = (N + 255) / 256;  // scan phase-1 blocks
    int* flags  = (int*)take(4 * 4);
    int* rowptr = (int*)take((size_t)(N + 1) * 4);
    int* cursor = (int*)take((size_t)N * 4);
    int* deg    = (int*)take((size_t)N * 4);
    int* bsum   = (int*)take((size_t)nb1 * 4);
    int* boff   = (int*)take((size_t)nb1 * 4);
    int* col    = (int*)take((size_t)E * 4);
    int* bounds = (int*)take((size_t)(G + 1) * 4);
    float* Z    = (float*)take((size_t)G * 128 * 4);
    float* cW1T = (float*)take((size_t)128 * 128 * 4);
    float* P0   = (float*)take(384 * 4);
    float* P1   = (float*)take(384 * 4);
    float* P2   = (float*)take(192 * 4);
    float* PM   = (float*)take(386 * 4);
    ushort_t* Wb0 = (ushort_t*)take((size_t)128 * 256 * 2);
    ushort_t* Wb1 = (ushort_t*)take((size_t)128 * 256 * 2);
    ushort_t* Wb2 = (ushort_t*)take((size_t)128 * 128 * 2);
    ushort_t* AGG = (ushort_t*)take((size_t)N * 128 * 2);
    ushort_t* H1  = (ushort_t*)take((size_t)N * 128 * 2);
    ushort_t* H2  = (ushort_t*)take((size_t)N * 128 * 2);
    ushort_t* XB  = H2;   // x-as-bf16 overlays H2 (dead before H2 written)
    ushort_t* T3  = AGG;  // layer-3 GEMM out overlays AGG (dead after layer-2 gemm)
    ushort_t* H3  = H1;   // [N,64] reuses H1
    if (o > ws_size) return;

    int eb = (E + 255) / 256;
    int xb = (N * 128 / 4 + 255) / 256;
    int wtot = 2 * 32768 + 16384 + 16384 + 1346;
    int wb = (wtot + 255) / 256;
    k_detect_zero<<<nb1, 256, 0, stream>>>(Wl0, ei, flags, deg, Z, N);
    k_prep<<<xb + eb + wb, 256, 0, stream>>>(x, XB, N * 128 / 4, xb,
                                             ei, E, N, deg, eb,
                                             Wl0, Wr0, Wl1, Wr1, Wl2, Wr2, cW1,
                                             bl0, g0, be0, bl1, g1, be1, bl2, g2, be2,
                                             cb1, cW2, cb2,
                                             Wb0, Wb1, Wb2, cW1T, P0, P1, P2, PM, flags);
    k_scan1<<<nb1, 256, 0, stream>>>(deg, N, rowptr, bsum);
    k_scan2<<<1, 256, 0, stream>>>(bsum, nb1, boff, rowptr + N, batch, N, G, flags, bounds);
    k_scan3<<<nb1, 256, 0, stream>>>(rowptr, boff, cursor, N);
    k_fill<<<eb, 256, 0, stream>>>(ei, E, N, flags, cursor, col);

    int gb = (N + 127) / 128;  // gemm blocks (4 waves x 32 rows)
    int ab = (N + 3) / 4;      // agg blocks (4 waves = 4 nodes each)

    // layer 0: XB -> H1
    k_agg<<<ab, 256, 0, stream>>>(XB, rowptr, col, AGG, N);
    k_gemm_ln<128><<<gb, 256, 0, stream>>>(AGG, XB, Wb0, P0, H1, N);
    // layer 1: H1 -> H2 (overwrites XB; XB dead)
    k_agg<<<ab, 256, 0, stream>>>(H1, rowptr, col, AGG, N);
    k_gemm_ln<128><<<gb, 256, 0, stream>>>(AGG, H1, Wb1, P1, H2, N);
    // layer 2 (reordered): T3 = H2 @ [Wl2;Wr2]^T, then aggregate + epilogue
    k_gemm3<<<gb, 256, 0, stream>>>(H2, Wb2, T3, N);
    k_agg3<<<ab, 256, 0, stream>>>(T3, rowptr, col, P2, H3, N);

    k_pool<<<G * 16, 256, 0, stream>>>(H3, bounds, Z, N);
    k_mlp<<<G, 128, 0, stream>>>(Z, bounds, cW1T, PM, flags, d_out);
}